// Round 1
// 883.441 us; speedup vs baseline: 1.1637x; 1.1637x over previous
//
#include <hip/hip_runtime.h>
#include <math.h>

// N=511 complete binary tree: nodes 0..254 internal (both children valid),
// 255..510 leaves. B=128, M=256, IN=512, R=64.
// Gate-interleaved bf16 weight layouts fuse every LSTM-cell epilogue into its
// producing GEMM. GEMM staging uses global_load_lds width=16 (async direct-to-
// LDS, no VGPR round trip). LDS tiles are unpadded (stride 64 shorts) with an
// XOR k-slot swizzle (slot = kc ^ ((row&7)*8)) compensated in the per-lane
// global source address, so frag ds_read_b128 stays bank-conflict-free.
// Round 5: (a) libm expf/tanhf -> v_exp_f32/v_rcp_f32 forms (epilogue was
// VALU-bound: VALUBusy 33% vs MfmaUtil 9%); (b) XCD-aware block remap so the
// 8 column-blocks sharing an A row-tile land on ONE XCD's L2 (FETCH was 4x
// ideal: 137 MB vs 34 MB on k_leaf).
#define NNODE 511

typedef short s16x8 __attribute__((ext_vector_type(8)));
typedef float f32x4 __attribute__((ext_vector_type(4)));

__device__ __forceinline__ unsigned short f2bf(float f) {
  unsigned int u = __builtin_bit_cast(unsigned int, f);
  u += 0x7fffu + ((u >> 16) & 1u);           // RNE
  return (unsigned short)(u >> 16);
}
// Fast sigmoid/tanh via v_exp_f32 (2^x) + v_rcp_f32. ~1 ulp vs libm; exact
// saturation at +-inf (rcp(inf)=0).
__device__ __forceinline__ float sigf(float x) {
  float e = __builtin_amdgcn_exp2f(-1.442695040888963f * x);
  return __builtin_amdgcn_rcpf(1.0f + e);
}
__device__ __forceinline__ float tanh_a(float x) {
  float e = __builtin_amdgcn_exp2f(2.885390081777927f * x);
  return 1.0f - 2.0f * __builtin_amdgcn_rcpf(1.0f + e);
}

__device__ __forceinline__ void load16_lds(const unsigned short* g, unsigned short* l) {
  __builtin_amdgcn_global_load_lds(
      (const __attribute__((address_space(1))) void*)g,
      (__attribute__((address_space(3))) void*)l, 16, 0, 0);
}

// XCD-aware block remap. Grid is always (8, ny). Linear dispatch round-robins
// consecutive linear IDs across the 8 XCDs, so with x-fastest order the 8
// column blocks sharing one A row-tile land on 8 different L2s. Remap so XCD k
// owns by in [k*ny/8,(k+1)*ny/8) x all bx (bijective; only when ny%8==0 --
// small tail launches don't matter, everything L2-fits there anyway).
__device__ __forceinline__ void swz_blk(int& bx, int& by) {
  bx = blockIdx.x; by = blockIdx.y;
  int ny = gridDim.y;
  if ((ny & 7) == 0) {
    int lin = by * 8 + bx;
    int w = lin >> 3;
    by = (lin & 7) * (ny >> 3) + (w >> 3);
    bx = w & 7;
  }
}

// ---------------------------------------------------------------------------
// wte (B,511,512) fp32 -> xbf (node,b,k) bf16, node-major. One-time.
__global__ void k_prep_x(const float* __restrict__ w, unsigned short* __restrict__ xbf) {
  int o = (blockIdx.x * 256 + threadIdx.x) * 4;   // out elem: node*65536 + b*512 + k
  int node = o >> 16;
  int b = (o >> 9) & 127;
  int k = o & 511;
  const float4 v = *(const float4*)(w + ((size_t)b * NNODE + node) * 512 + k);
  unsigned int p0 = (unsigned int)f2bf(v.x) | ((unsigned int)f2bf(v.y) << 16);
  unsigned int p1 = (unsigned int)f2bf(v.z) | ((unsigned int)f2bf(v.w) << 16);
  *(uint2*)(xbf + o) = make_uint2(p0, p1);
}

// ---------------------------------------------------------------------------
// Gate-interleaved transposed weights (c = column index, k = reduction index):
//  WL2t (768,512):  c = 48G+16g+mi, g in {i,u,o}
//  WA2t (1280,320): c = 80G+16g+mi, g in {i,f,g,o,fh}
//  WH2t (1024,256): c = 64G+16g+mi, g in {i,f,g,o}
//  WEX2t(1024,768): c = 64G+16g+mi, g in {i,u,o,f}; k<256 h-weights, k>=256 x-weights
__global__ void k_prep_w(const float* __restrict__ Wix, const float* __restrict__ Wux,
                         const float* __restrict__ Wox, const float* __restrict__ Wfx,
                         const float* __restrict__ Wih, const float* __restrict__ Wuh,
                         const float* __restrict__ Woh, const float* __restrict__ Wfh,
                         const float* __restrict__ Wsi, const float* __restrict__ Wsh,
                         unsigned short* __restrict__ WL2t, unsigned short* __restrict__ WA2t,
                         unsigned short* __restrict__ WH2t, unsigned short* __restrict__ WEX2t) {
  int idx = blockIdx.x * 256 + threadIdx.x;
  if (idx < 393216) {                       // WL2t 768*512
    int c = idx >> 9, k = idx & 511;
    int G = c / 48, rem = c - G * 48, g = rem >> 4, mi = rem & 15, m = G * 16 + mi;
    const float* W = (g == 0) ? Wix : (g == 1) ? Wux : Wox;
    WL2t[idx] = f2bf(W[k * 256 + m]);
  } else if (idx < 802816) {                // WA2t 1280*320
    int o = idx - 393216;
    int c = o / 320, k = o - c * 320;
    int G = c / 80, rem = c - G * 80, g = rem >> 4, mi = rem & 15, m = G * 16 + mi;
    float v;
    if (g < 4) v = Wsi[k * 1024 + g * 256 + m];
    else       v = (k < 256) ? Wfh[k * 256 + m] : 0.0f;
    WA2t[o] = f2bf(v);
  } else if (idx < 1064960) {               // WH2t 1024*256
    int o = idx - 802816;
    int c = o >> 8, k = o & 255;
    int G = c >> 6, rem = c & 63, g = rem >> 4, mi = rem & 15, m = G * 16 + mi;
    WH2t[o] = f2bf(Wsh[k * 1024 + g * 256 + m]);
  } else if (idx < 1851392) {               // WEX2t 1024*768
    int o = idx - 1064960;
    int c = o / 768, k = o - c * 768;
    int G = c >> 6, rem = c & 63, g = rem >> 4, mi = rem & 15, m = G * 16 + mi;
    float v;
    if (k < 256) {
      v = (g == 0) ? Wih[k * 256 + m] : (g == 1) ? Wuh[k * 256 + m]
        : (g == 2) ? Woh[k * 256 + m] : 0.0f;
    } else {
      int k2 = k - 256;
      v = (g == 0) ? Wix[k2 * 256 + m] : (g == 1) ? Wux[k2 * 256 + m]
        : (g == 2) ? Wox[k2 * 256 + m] : Wfx[k2 * 256 + m];
    }
    WEX2t[o] = f2bf(v);
  }
}

// Swizzled MFMA inner step. LDS row stride 64 shorts; k-slot XOR swizzle.
// sw(kk) = (kk | q*8) ^ ((m16&7)*8); row&7 == m16&7 for all our row bases
// (wave row offsets are multiples of 8).
#define MFMA_BODY(NG, CW)                                                     \
  _Pragma("unroll")                                                           \
  for (int kk = 0; kk < 64; kk += 32) {                                       \
    const int sw = (kk | (q * 8)) ^ ((m16 & 7) * 8);                          \
    s16x8 af[4], bfr[NG];                                                     \
    _Pragma("unroll")                                                         \
    for (int i = 0; i < 4; ++i)                                               \
      af[i] = *(const s16x8*)(&As[(wm + i * 16 + m16) * 64 + sw]);            \
    _Pragma("unroll")                                                         \
    for (int j = 0; j < NG; ++j)                                              \
      bfr[j] = *(const s16x8*)(&Bs[(wc * CW + j * 16 + m16) * 64 + sw]);      \
    _Pragma("unroll")                                                         \
    for (int i = 0; i < 4; ++i)                                               \
      _Pragma("unroll")                                                       \
      for (int j = 0; j < NG; ++j)                                            \
        acc[i][j] = __builtin_amdgcn_mfma_f32_16x16x32_bf16(af[i], bfr[j], acc[i][j], 0, 0, 0); \
  }

// Stage R rows x 64 shorts from SRC (row stride STRIDE shorts, starting global
// row 0 of SRC, k offset k0) into DST via global_load_lds. Wave w covers rows
// [w*R/4, (w+1)*R/4), 8 rows per instruction. l8/l7/gsw precomputed.
#define STAGE(DST, SRC, STRIDE, R)                                            \
  _Pragma("unroll")                                                           \
  for (int c = 0; c < (R) / 32; ++c) {                                        \
    int row8 = wave * ((R) / 4) + c * 8;                                      \
    load16_lds(SRC + (size_t)(row8 + l8) * (STRIDE) + k0 + gsw, &DST[row8 * 64]); \
  }

// ---------------------------------------------------------------------------
// GEMM1 + cell1 epilogue. A = [AinL ; AinR] (2*crows x 320 bf16), B = WA2t.
// L rows -> h1 (bf16), c1, FHL.  R rows -> PR (float4 i,f,g,o preacts), FHR.
__global__ __launch_bounds__(256) void k_gemm1(
    const unsigned short* __restrict__ AinL, const unsigned short* __restrict__ AinR,
    const unsigned short* __restrict__ Bt,
    unsigned short* __restrict__ h1, float* __restrict__ c1,
    float* __restrict__ FHL, float* __restrict__ FHR, float* __restrict__ PR,
    const float* __restrict__ bsi, const float* __restrict__ bsh, int crows) {
  __shared__ alignas(16) unsigned short As[128 * 64];
  __shared__ alignas(16) unsigned short Bs[160 * 64];
  int bx, by; swz_blk(bx, by);
  const int t = threadIdx.x;
  const int wave = t >> 6, lane = t & 63;
  const int wm = (wave & 1) * 64, wc = wave >> 1;
  const int m16 = lane & 15, q = lane >> 4;
  const int l8 = lane >> 3, l7 = lane & 7;
  const int gsw = ((l7 ^ l8) * 8);
  const int rowBase = by * 128;
  const bool isL = rowBase < crows;
  const unsigned short* Arow = isL ? (AinL + (size_t)rowBase * 320)
                                   : (AinR + (size_t)(rowBase - crows) * 320);
  const unsigned short* Brow = Bt + (size_t)bx * 160 * 320;
  f32x4 acc[4][5] = {};

  for (int k0 = 0; k0 < 320; k0 += 64) {
    STAGE(As, Arow, 320, 128)
    STAGE(Bs, Brow, 320, 160)
    __syncthreads();
    MFMA_BODY(5, 80)
    __syncthreads();
  }

  const int m = (bx * 2 + wc) * 16 + m16;
  if (isL) {
    float bi = bsi[m] + bsh[m];
    float bg = bsi[512 + m] + bsh[512 + m];
    float bo = bsi[768 + m] + bsh[768 + m];
#pragma unroll
    for (int i = 0; i < 4; ++i)
#pragma unroll
      for (int r2 = 0; r2 < 4; ++r2) {
        int r = rowBase + wm + i * 16 + q * 4 + r2;
        float ii = sigf(acc[i][0][r2] + bi);
        float gg = tanh_a(acc[i][2][r2] + bg);
        float oo = sigf(acc[i][3][r2] + bo);
        float cv = ii * gg;
        size_t o = (size_t)r * 256 + m;
        h1[o] = f2bf(oo * tanh_a(cv));
        c1[o] = cv;
        FHL[o] = acc[i][4][r2];
      }
  } else {
#pragma unroll
    for (int i = 0; i < 4; ++i)
#pragma unroll
      for (int r2 = 0; r2 < 4; ++r2) {
        int rr = rowBase - crows + wm + i * 16 + q * 4 + r2;
        size_t o = (size_t)rr * 256 + m;
        float4 pv = {acc[i][0][r2], acc[i][1][r2], acc[i][2][r2], acc[i][3][r2]};
        *(float4*)(PR + o * 4) = pv;
        FHR[o] = acc[i][4][r2];
      }
  }
}

// ---------------------------------------------------------------------------
// GEMM2 + cell2 epilogue. A = h1 (crows x 256), B = WH2t.
// g = acc + PR + b_seq; h_tilde -> HT (bf16).
__global__ __launch_bounds__(256) void k_gemm2(
    const unsigned short* __restrict__ A, const unsigned short* __restrict__ Bt,
    const float* __restrict__ PR, const float* __restrict__ c1,
    unsigned short* __restrict__ HT,
    const float* __restrict__ bsi, const float* __restrict__ bsh) {
  __shared__ alignas(16) unsigned short As[128 * 64];
  __shared__ alignas(16) unsigned short Bs[128 * 64];
  int bx, by; swz_blk(bx, by);
  const int t = threadIdx.x;
  const int wave = t >> 6, lane = t & 63;
  const int wm = (wave & 1) * 64, wc = wave >> 1;
  const int m16 = lane & 15, q = lane >> 4;
  const int l8 = lane >> 3, l7 = lane & 7;
  const int gsw = ((l7 ^ l8) * 8);
  const int rowBase = by * 128;
  const unsigned short* Arow = A + (size_t)rowBase * 256;
  const unsigned short* Brow = Bt + (size_t)bx * 128 * 256;
  f32x4 acc[4][4] = {};

  for (int k0 = 0; k0 < 256; k0 += 64) {
    STAGE(As, Arow, 256, 128)
    STAGE(Bs, Brow, 256, 128)
    __syncthreads();
    MFMA_BODY(4, 64)
    __syncthreads();
  }

  const int m = (bx * 2 + wc) * 16 + m16;
  float b0 = bsi[m] + bsh[m];
  float b1 = bsi[256 + m] + bsh[256 + m];
  float b2 = bsi[512 + m] + bsh[512 + m];
  float b3 = bsi[768 + m] + bsh[768 + m];
#pragma unroll
  for (int i = 0; i < 4; ++i)
#pragma unroll
    for (int r2 = 0; r2 < 4; ++r2) {
      int r = rowBase + wm + i * 16 + q * 4 + r2;
      size_t o = (size_t)r * 256 + m;
      float4 pv = *(const float4*)(PR + o * 4);
      float ii = sigf(acc[i][0][r2] + pv.x + b0);
      float ff = sigf(acc[i][1][r2] + pv.y + b1);
      float gg = tanh_a(acc[i][2][r2] + pv.z + b2);
      float oo = sigf(acc[i][3][r2] + pv.w + b3);
      float c2 = ff * c1[o] + ii * gg;
      HT[o] = f2bf(oo * tanh_a(c2));
    }
}

// ---------------------------------------------------------------------------
// GEMM3 + node-gate epilogue. A = [HT | xbf-slice] (crows x 768 bf16),
// B = WEX2t (gates i,u,o,f). Uses FHL/FHR + children cbuf.
// lvl>0: write cbuf + parent Ain (h bf16, rel). lvl==0: write d_out fp32.
__global__ __launch_bounds__(256) void k_gemm3(
    const unsigned short* __restrict__ HT, const unsigned short* __restrict__ xnode,
    const unsigned short* __restrict__ Bt,
    const float* __restrict__ FHL, const float* __restrict__ FHR,
    float* __restrict__ cbuf, unsigned short* __restrict__ Ain,
    const float* __restrict__ rel, float* __restrict__ out,
    const float* __restrict__ bix, const float* __restrict__ bih,
    const float* __restrict__ bux, const float* __restrict__ buh,
    const float* __restrict__ box, const float* __restrict__ boh,
    const float* __restrict__ bfx, const float* __restrict__ bfh,
    int base, int v0, int n, int lvl) {
  __shared__ alignas(16) unsigned short As[128 * 64];
  __shared__ alignas(16) unsigned short Bs[128 * 64];
  int bx, by; swz_blk(bx, by);
  const int t = threadIdx.x;
  const int wave = t >> 6, lane = t & 63;
  const int wm = (wave & 1) * 64, wc = wave >> 1;
  const int m16 = lane & 15, q = lane >> 4;
  const int l8 = lane >> 3, l7 = lane & 7;
  const int gsw = ((l7 ^ l8) * 8);
  const int rowBase = by * 128;
  const unsigned short* Brow = Bt + (size_t)bx * 128 * 768;
  f32x4 acc[4][4] = {};

  for (int kb = 0; kb < 768; kb += 64) {
    {
      // A source: k<256 from HT (stride 256), k>=256 from xnode (stride 512).
      const unsigned short* Arow;
      int k0;
      if (kb < 256) { Arow = HT + (size_t)rowBase * 256;    k0 = kb; 
#pragma unroll
        for (int c = 0; c < 4; ++c) {
          int row8 = wave * 32 + c * 8;
          load16_lds(Arow + (size_t)(row8 + l8) * 256 + k0 + gsw, &As[row8 * 64]);
        }
      } else {        Arow = xnode + (size_t)rowBase * 512; k0 = kb - 256;
#pragma unroll
        for (int c = 0; c < 4; ++c) {
          int row8 = wave * 32 + c * 8;
          load16_lds(Arow + (size_t)(row8 + l8) * 512 + k0 + gsw, &As[row8 * 64]);
        }
      }
    }
    {
      int k0 = kb;
      STAGE(Bs, Brow, 768, 128)
    }
    __syncthreads();
    MFMA_BODY(4, 64)
    __syncthreads();
  }

  const int m = (bx * 2 + wc) * 16 + m16;
  float bi = bix[m] + bih[m];
  float bu = bux[m] + buh[m];
  float bo = box[m] + boh[m];
  float bf = bfx[m] + bfh[m];
#pragma unroll
  for (int i = 0; i < 4; ++i)
#pragma unroll
    for (int r2 = 0; r2 < 4; ++r2) {
      int r = rowBase + wm + i * 16 + q * 4 + r2;
      int vloc = r >> 7, b = r & 127;
      int vg = v0 + vloc;
      int node = base + vg;
      int ch0 = 2 * node + 1;
      size_t o = (size_t)r * 256 + m;
      float pf = acc[i][3][r2] + bf;
      float f0 = sigf(pf + FHL[o]);
      float f1 = sigf(pf + FHR[o]);
      float ii = sigf(acc[i][0][r2] + bi);
      float uu = tanh_a(acc[i][1][r2] + bu);
      float oo = sigf(acc[i][2][r2] + bo);
      float cc = ii * uu + f0 * cbuf[((size_t)ch0 * 128 + b) * 256 + m]
                         + f1 * cbuf[((size_t)(ch0 + 1) * 128 + b) * 256 + m];
      float hh = oo * tanh_a(cc);
      if (lvl == 0) {
        out[b * 256 + m] = hh;
      } else {
        cbuf[((size_t)node * 128 + b) * 256 + m] = cc;
        int rowA = (vg & 1) * (n >> 1) * 128 + (vg >> 1) * 128 + b;
        Ain[(size_t)rowA * 320 + m] = f2bf(hh);
        if (m < 64)
          Ain[(size_t)rowA * 320 + 256 + m] = f2bf(rel[((size_t)b * NNODE + node) * 64 + m]);
      }
    }
}

// ---------------------------------------------------------------------------
// Leaf GEMM + epilogue. A = xbf leaf slice (32768 x 512 bf16), B = WL2t
// (gates i,u,o). c = i*u; writes cbuf + level-7 Ain.
__global__ __launch_bounds__(256) void k_leaf(
    const unsigned short* __restrict__ xleaf, const unsigned short* __restrict__ Bt,
    float* __restrict__ cbuf, unsigned short* __restrict__ Ain,
    const float* __restrict__ rel,
    const float* __restrict__ bix, const float* __restrict__ bih,
    const float* __restrict__ bux, const float* __restrict__ buh,
    const float* __restrict__ box, const float* __restrict__ boh) {
  __shared__ alignas(16) unsigned short As[128 * 64];
  __shared__ alignas(16) unsigned short Bs[96 * 64];
  int bx, by; swz_blk(bx, by);
  const int t = threadIdx.x;
  const int wave = t >> 6, lane = t & 63;
  const int wm = (wave & 1) * 64, wc = wave >> 1;
  const int m16 = lane & 15, q = lane >> 4;
  const int l8 = lane >> 3, l7 = lane & 7;
  const int gsw = ((l7 ^ l8) * 8);
  const int rowBase = by * 128;
  const unsigned short* Arow = xleaf + (size_t)rowBase * 512;
  const unsigned short* Brow = Bt + (size_t)bx * 96 * 512;
  f32x4 acc[4][3] = {};

  for (int k0 = 0; k0 < 512; k0 += 64) {
    STAGE(As, Arow, 512, 128)
    // B: 96 rows -> 24 rows/wave = 3 instrs
#pragma unroll
    for (int c = 0; c < 3; ++c) {
      int row8 = wave * 24 + c * 8;
      load16_lds(Brow + (size_t)(row8 + l8) * 512 + k0 + gsw, &Bs[row8 * 64]);
    }
    __syncthreads();
    MFMA_BODY(3, 48)
    __syncthreads();
  }

  const int m = (bx * 2 + wc) * 16 + m16;
  float bi = bix[m] + bih[m];
  float bu = bux[m] + buh[m];
  float bo = box[m] + boh[m];
#pragma unroll
  for (int i = 0; i < 4; ++i)
#pragma unroll
    for (int r2 = 0; r2 < 4; ++r2) {
      int r = rowBase + wm + i * 16 + q * 4 + r2;
      int vg = r >> 7, b = r & 127;
      int node = 255 + vg;
      float ii = sigf(acc[i][0][r2] + bi);
      float uu = tanh_a(acc[i][1][r2] + bu);
      float oo = sigf(acc[i][2][r2] + bo);
      float cc = ii * uu;
      float hh = oo * tanh_a(cc);
      cbuf[((size_t)node * 128 + b) * 256 + m] = cc;
      int rowA = (vg & 1) * 16384 + (vg >> 1) * 128 + b;
      Ain[(size_t)rowA * 320 + m] = f2bf(hh);
      if (m < 64)
        Ain[(size_t)rowA * 320 + 256 + m] = f2bf(rel[((size_t)b * NNODE + node) * 64 + m]);
    }
}

// ---------------------------------------------------------------------------
extern "C" void kernel_launch(void* const* d_in, const int* in_sizes, int n_in,
                              void* d_out, int out_size, void* d_ws, size_t ws_size,
                              hipStream_t stream) {
  const float* wte = (const float*)d_in[0];
  const float* rel = (const float*)d_in[1];
  const float* Wix = (const float*)d_in[3];
  const float* bix = (const float*)d_in[4];
  const float* Wfx = (const float*)d_in[5];
  const float* bfx = (const float*)d_in[6];
  const float* Wux = (const float*)d_in[7];
  const float* bux = (const float*)d_in[8];
  const float* Wox = (const float*)d_in[9];
  const float* box = (const float*)d_in[10];
  const float* Wih = (const float*)d_in[11];
  const float* bih = (const float*)d_in[12];
  const float* Wfh = (const float*)d_in[13];
  const float* bfh = (const float*)d_in[14];
  const float* Wuh = (const float*)d_in[15];
  const float* buh = (const float*)d_in[16];
  const float* Woh = (const float*)d_in[17];
  const float* boh = (const float*)d_in[18];
  const float* Wsi = (const float*)d_in[19];
  const float* Wsh = (const float*)d_in[20];
  const float* bsi = (const float*)d_in[21];
  const float* bsh = (const float*)d_in[22];
  float* out = (float*)d_out;
  (void)in_sizes; (void)n_in; (void)out_size;

  int INT_MAXN;
  if (ws_size >= (size_t)310 * 1024 * 1024)      INT_MAXN = 128;
  else if (ws_size >= (size_t)200 * 1024 * 1024) INT_MAXN = 32;
  else                                           INT_MAXN = 8;
  const int crowsMax = INT_MAXN * 128;

  char* ws = (char*)d_ws;
  size_t off = 0;
  auto alloc = [&](size_t bytes) {
    size_t o = off; off += (bytes + 255) & ~(size_t)255; return o;
  };
  unsigned short* xbf  = (unsigned short*)(ws + alloc((size_t)NNODE * 128 * 512 * 2));
  float*          cbuf = (float*)         (ws + alloc((size_t)NNODE * 128 * 256 * 4));
  unsigned short* Ain  = (unsigned short*)(ws + alloc((size_t)32768 * 320 * 2));
  unsigned short* WL2t = (unsigned short*)(ws + alloc((size_t)768 * 512 * 2));
  unsigned short* WA2t = (unsigned short*)(ws + alloc((size_t)1280 * 320 * 2));
  unsigned short* WH2t = (unsigned short*)(ws + alloc((size_t)1024 * 256 * 2));
  unsigned short* WEX2t= (unsigned short*)(ws + alloc((size_t)1024 * 768 * 2));
  unsigned short* h1   = (unsigned short*)(ws + alloc((size_t)crowsMax * 256 * 2));
  float*          c1   = (float*)         (ws + alloc((size_t)crowsMax * 256 * 4));
  float*          FHL  = (float*)         (ws + alloc((size_t)crowsMax * 256 * 4));
  float*          FHR  = (float*)         (ws + alloc((size_t)crowsMax * 256 * 4));
  float*          PR   = (float*)         (ws + alloc((size_t)crowsMax * 1024 * 4));
  unsigned short* HT   = (unsigned short*)(ws + alloc((size_t)crowsMax * 256 * 2));

  k_prep_x<<<32704, 256, 0, stream>>>(wte, xbf);
  k_prep_w<<<7232, 256, 0, stream>>>(Wix, Wux, Wox, Wfx, Wih, Wuh, Woh, Wfh,
                                     Wsi, Wsh, WL2t, WA2t, WH2t, WEX2t);

  // Leaves: one fused GEMM over xbf rows [255*128, 511*128).
  k_leaf<<<dim3(8, 256), 256, 0, stream>>>(xbf + (size_t)255 * 128 * 512, WL2t,
                                           cbuf, Ain, rel, bix, bih, bux, buh, box, boh);

  // Internal levels 7..0, 3 fused launches per chunk.
  for (int lvl = 7; lvl >= 0; --lvl) {
    int n = 1 << lvl;
    int base = n - 1;
    int cn = (n < INT_MAXN) ? n : INT_MAXN;
    for (int v0 = 0; v0 < n; v0 += cn) {
      int crows = cn * 128;
      const unsigned short* AinL = Ain + (size_t)(v0 * 128) * 320;
      const unsigned short* AinR = Ain + (size_t)((n + v0) * 128) * 320;
      const unsigned short* xnode = xbf + (size_t)(base + v0) * 128 * 512;
      k_gemm1<<<dim3(8, 2 * cn), 256, 0, stream>>>(AinL, AinR, WA2t, h1, c1,
                                                   FHL, FHR, PR, bsi, bsh, crows);
      k_gemm2<<<dim3(8, cn), 256, 0, stream>>>(h1, WH2t, PR, c1, HT, bsi, bsh);
      k_gemm3<<<dim3(8, cn), 256, 0, stream>>>(HT, xnode, WEX2t, FHL, FHR, cbuf, Ain,
                                               rel, out, bix, bih, bux, buh, box, boh,
                                               bfx, bfh, base, v0, n, lvl);
    }
  }
}

// Round 2
// 788.659 us; speedup vs baseline: 1.3036x; 1.1202x over previous
//
#include <hip/hip_runtime.h>
#include <math.h>

// N=511 complete binary tree: nodes 0..254 internal (both children valid),
// 255..510 leaves. B=128, M=256, IN=512, R=64.
// Gate-interleaved bf16 weight layouts fuse every LSTM-cell epilogue into its
// producing GEMM. GEMM staging uses global_load_lds width=16 (async direct-to-
// LDS). LDS tiles are unpadded (stride 64 shorts) with an XOR k-slot swizzle
// compensated in the per-lane global source address (ds_read_b128 conflict-free).
// Round 5: fast exp2/rcp transcendentals + XCD block remap (VALU 33->14%).
// Round 6: T3/T4 minimum-2-phase double-buffered K-loop. Old structure was
// STAGE -> barrier(vmcnt0 drain) -> MFMA -> barrier: every K-step exposed the
// full global_load_lds latency (MfmaUtil 12% == pure-MFMA floor / dur). Now:
// issue next-tile STAGE into ping-pong buffer BEFORE the MFMA cluster; one
// barrier per K-step whose vmcnt(0) lands after MFMA hides the load latency.
#define NNODE 511

typedef short s16x8 __attribute__((ext_vector_type(8)));
typedef float f32x4 __attribute__((ext_vector_type(4)));

__device__ __forceinline__ unsigned short f2bf(float f) {
  unsigned int u = __builtin_bit_cast(unsigned int, f);
  u += 0x7fffu + ((u >> 16) & 1u);           // RNE
  return (unsigned short)(u >> 16);
}
// Fast sigmoid/tanh via v_exp_f32 (2^x) + v_rcp_f32. ~1 ulp vs libm; exact
// saturation at +-inf (rcp(inf)=0).
__device__ __forceinline__ float sigf(float x) {
  float e = __builtin_amdgcn_exp2f(-1.442695040888963f * x);
  return __builtin_amdgcn_rcpf(1.0f + e);
}
__device__ __forceinline__ float tanh_a(float x) {
  float e = __builtin_amdgcn_exp2f(2.885390081777927f * x);
  return 1.0f - 2.0f * __builtin_amdgcn_rcpf(1.0f + e);
}

__device__ __forceinline__ void load16_lds(const unsigned short* g, unsigned short* l) {
  __builtin_amdgcn_global_load_lds(
      (const __attribute__((address_space(1))) void*)g,
      (__attribute__((address_space(3))) void*)l, 16, 0, 0);
}

// XCD-aware block remap. Grid is always (8, ny). Remap so XCD k owns a
// contiguous by-range x all bx (bijective when ny%8==0; tail launches L2-fit).
__device__ __forceinline__ void swz_blk(int& bx, int& by) {
  bx = blockIdx.x; by = blockIdx.y;
  int ny = gridDim.y;
  if ((ny & 7) == 0) {
    int lin = by * 8 + bx;
    int w = lin >> 3;
    by = (lin & 7) * (ny >> 3) + (w >> 3);
    bx = w & 7;
  }
}

// ---------------------------------------------------------------------------
// wte (B,511,512) fp32 -> xbf (node,b,k) bf16, node-major. One-time.
__global__ void k_prep_x(const float* __restrict__ w, unsigned short* __restrict__ xbf) {
  int o = (blockIdx.x * 256 + threadIdx.x) * 4;   // out elem: node*65536 + b*512 + k
  int node = o >> 16;
  int b = (o >> 9) & 127;
  int k = o & 511;
  const float4 v = *(const float4*)(w + ((size_t)b * NNODE + node) * 512 + k);
  unsigned int p0 = (unsigned int)f2bf(v.x) | ((unsigned int)f2bf(v.y) << 16);
  unsigned int p1 = (unsigned int)f2bf(v.z) | ((unsigned int)f2bf(v.w) << 16);
  *(uint2*)(xbf + o) = make_uint2(p0, p1);
}

// ---------------------------------------------------------------------------
// Gate-interleaved transposed weights (c = column index, k = reduction index):
//  WL2t (768,512):  c = 48G+16g+mi, g in {i,u,o}
//  WA2t (1280,320): c = 80G+16g+mi, g in {i,f,g,o,fh}
//  WH2t (1024,256): c = 64G+16g+mi, g in {i,f,g,o}
//  WEX2t(1024,768): c = 64G+16g+mi, g in {i,u,o,f}; k<256 h-weights, k>=256 x-weights
__global__ void k_prep_w(const float* __restrict__ Wix, const float* __restrict__ Wux,
                         const float* __restrict__ Wox, const float* __restrict__ Wfx,
                         const float* __restrict__ Wih, const float* __restrict__ Wuh,
                         const float* __restrict__ Woh, const float* __restrict__ Wfh,
                         const float* __restrict__ Wsi, const float* __restrict__ Wsh,
                         unsigned short* __restrict__ WL2t, unsigned short* __restrict__ WA2t,
                         unsigned short* __restrict__ WH2t, unsigned short* __restrict__ WEX2t) {
  int idx = blockIdx.x * 256 + threadIdx.x;
  if (idx < 393216) {                       // WL2t 768*512
    int c = idx >> 9, k = idx & 511;
    int G = c / 48, rem = c - G * 48, g = rem >> 4, mi = rem & 15, m = G * 16 + mi;
    const float* W = (g == 0) ? Wix : (g == 1) ? Wux : Wox;
    WL2t[idx] = f2bf(W[k * 256 + m]);
  } else if (idx < 802816) {                // WA2t 1280*320
    int o = idx - 393216;
    int c = o / 320, k = o - c * 320;
    int G = c / 80, rem = c - G * 80, g = rem >> 4, mi = rem & 15, m = G * 16 + mi;
    float v;
    if (g < 4) v = Wsi[k * 1024 + g * 256 + m];
    else       v = (k < 256) ? Wfh[k * 256 + m] : 0.0f;
    WA2t[o] = f2bf(v);
  } else if (idx < 1064960) {               // WH2t 1024*256
    int o = idx - 802816;
    int c = o >> 8, k = o & 255;
    int G = c >> 6, rem = c & 63, g = rem >> 4, mi = rem & 15, m = G * 16 + mi;
    WH2t[o] = f2bf(Wsh[k * 1024 + g * 256 + m]);
  } else if (idx < 1851392) {               // WEX2t 1024*768
    int o = idx - 1064960;
    int c = o / 768, k = o - c * 768;
    int G = c >> 6, rem = c & 63, g = rem >> 4, mi = rem & 15, m = G * 16 + mi;
    float v;
    if (k < 256) {
      v = (g == 0) ? Wih[k * 256 + m] : (g == 1) ? Wuh[k * 256 + m]
        : (g == 2) ? Woh[k * 256 + m] : 0.0f;
    } else {
      int k2 = k - 256;
      v = (g == 0) ? Wix[k2 * 256 + m] : (g == 1) ? Wux[k2 * 256 + m]
        : (g == 2) ? Wox[k2 * 256 + m] : Wfx[k2 * 256 + m];
    }
    WEX2t[o] = f2bf(v);
  }
}

// Swizzled MFMA inner step reading buffers AP/BP. LDS row stride 64 shorts;
// k-slot XOR swizzle. sw(kk) = (kk | q*8) ^ ((m16&7)*8).
#define MFMA_BODY(AP, BP, NG, CW)                                             \
  _Pragma("unroll")                                                           \
  for (int kk = 0; kk < 64; kk += 32) {                                       \
    const int sw = (kk | (q * 8)) ^ ((m16 & 7) * 8);                          \
    s16x8 af[4], bfr[NG];                                                     \
    _Pragma("unroll")                                                         \
    for (int i = 0; i < 4; ++i)                                               \
      af[i] = *(const s16x8*)(&(AP)[(wm + i * 16 + m16) * 64 + sw]);          \
    _Pragma("unroll")                                                         \
    for (int j = 0; j < NG; ++j)                                              \
      bfr[j] = *(const s16x8*)(&(BP)[(wc * CW + j * 16 + m16) * 64 + sw]);    \
    _Pragma("unroll")                                                         \
    for (int i = 0; i < 4; ++i)                                               \
      _Pragma("unroll")                                                       \
      for (int j = 0; j < NG; ++j)                                            \
        acc[i][j] = __builtin_amdgcn_mfma_f32_16x16x32_bf16(af[i], bfr[j], acc[i][j], 0, 0, 0); \
  }

// Stage R rows x 64 shorts from SRC (row stride STRIDE shorts, k offset K0)
// into DST via global_load_lds. Wave w covers rows [w*R/4,(w+1)*R/4).
#define STAGE(DST, SRC, STRIDE, R, K0)                                        \
  _Pragma("unroll")                                                           \
  for (int c = 0; c < (R) / 32; ++c) {                                        \
    int row8 = wave * ((R) / 4) + c * 8;                                      \
    load16_lds(SRC + (size_t)(row8 + l8) * (STRIDE) + (K0) + gsw, &(DST)[row8 * 64]); \
  }

// ---------------------------------------------------------------------------
// GEMM1 + cell1 epilogue. A = [AinL ; AinR] (2*crows x 320 bf16), B = WA2t.
// L rows -> h1 (bf16), c1, FHL.  R rows -> PR (float4 i,f,g,o preacts), FHR.
__global__ __launch_bounds__(256) void k_gemm1(
    const unsigned short* __restrict__ AinL, const unsigned short* __restrict__ AinR,
    const unsigned short* __restrict__ Bt,
    unsigned short* __restrict__ h1, float* __restrict__ c1,
    float* __restrict__ FHL, float* __restrict__ FHR, float* __restrict__ PR,
    const float* __restrict__ bsi, const float* __restrict__ bsh, int crows) {
  __shared__ alignas(16) unsigned short As[2][128 * 64];
  __shared__ alignas(16) unsigned short Bs[2][160 * 64];
  int bx, by; swz_blk(bx, by);
  const int t = threadIdx.x;
  const int wave = t >> 6, lane = t & 63;
  const int wm = (wave & 1) * 64, wc = wave >> 1;
  const int m16 = lane & 15, q = lane >> 4;
  const int l8 = lane >> 3, l7 = lane & 7;
  const int gsw = ((l7 ^ l8) * 8);
  const int rowBase = by * 128;
  const bool isL = rowBase < crows;
  const unsigned short* Arow = isL ? (AinL + (size_t)rowBase * 320)
                                   : (AinR + (size_t)(rowBase - crows) * 320);
  const unsigned short* Brow = Bt + (size_t)bx * 160 * 320;
  f32x4 acc[4][5] = {};

  STAGE(As[0], Arow, 320, 128, 0)
  STAGE(Bs[0], Brow, 320, 160, 0)
  __syncthreads();
#pragma unroll
  for (int ti = 0; ti < 5; ++ti) {
    if (ti < 4) {
      STAGE(As[(ti + 1) & 1], Arow, 320, 128, (ti + 1) * 64)
      STAGE(Bs[(ti + 1) & 1], Brow, 320, 160, (ti + 1) * 64)
    }
    __builtin_amdgcn_sched_barrier(0);
    MFMA_BODY(As[ti & 1], Bs[ti & 1], 5, 80)
    __syncthreads();
  }

  const int m = (bx * 2 + wc) * 16 + m16;
  if (isL) {
    float bi = bsi[m] + bsh[m];
    float bg = bsi[512 + m] + bsh[512 + m];
    float bo = bsi[768 + m] + bsh[768 + m];
#pragma unroll
    for (int i = 0; i < 4; ++i)
#pragma unroll
      for (int r2 = 0; r2 < 4; ++r2) {
        int r = rowBase + wm + i * 16 + q * 4 + r2;
        float ii = sigf(acc[i][0][r2] + bi);
        float gg = tanh_a(acc[i][2][r2] + bg);
        float oo = sigf(acc[i][3][r2] + bo);
        float cv = ii * gg;
        size_t o = (size_t)r * 256 + m;
        h1[o] = f2bf(oo * tanh_a(cv));
        c1[o] = cv;
        FHL[o] = acc[i][4][r2];
      }
  } else {
#pragma unroll
    for (int i = 0; i < 4; ++i)
#pragma unroll
      for (int r2 = 0; r2 < 4; ++r2) {
        int rr = rowBase - crows + wm + i * 16 + q * 4 + r2;
        size_t o = (size_t)rr * 256 + m;
        float4 pv = {acc[i][0][r2], acc[i][1][r2], acc[i][2][r2], acc[i][3][r2]};
        *(float4*)(PR + o * 4) = pv;
        FHR[o] = acc[i][4][r2];
      }
  }
}

// ---------------------------------------------------------------------------
// GEMM2 + cell2 epilogue. A = h1 (crows x 256), B = WH2t.
// g = acc + PR + b_seq; h_tilde -> HT (bf16).
__global__ __launch_bounds__(256) void k_gemm2(
    const unsigned short* __restrict__ A, const unsigned short* __restrict__ Bt,
    const float* __restrict__ PR, const float* __restrict__ c1,
    unsigned short* __restrict__ HT,
    const float* __restrict__ bsi, const float* __restrict__ bsh) {
  __shared__ alignas(16) unsigned short As[2][128 * 64];
  __shared__ alignas(16) unsigned short Bs[2][128 * 64];
  int bx, by; swz_blk(bx, by);
  const int t = threadIdx.x;
  const int wave = t >> 6, lane = t & 63;
  const int wm = (wave & 1) * 64, wc = wave >> 1;
  const int m16 = lane & 15, q = lane >> 4;
  const int l8 = lane >> 3, l7 = lane & 7;
  const int gsw = ((l7 ^ l8) * 8);
  const int rowBase = by * 128;
  const unsigned short* Arow = A + (size_t)rowBase * 256;
  const unsigned short* Brow = Bt + (size_t)bx * 128 * 256;
  f32x4 acc[4][4] = {};

  STAGE(As[0], Arow, 256, 128, 0)
  STAGE(Bs[0], Brow, 256, 128, 0)
  __syncthreads();
#pragma unroll
  for (int ti = 0; ti < 4; ++ti) {
    if (ti < 3) {
      STAGE(As[(ti + 1) & 1], Arow, 256, 128, (ti + 1) * 64)
      STAGE(Bs[(ti + 1) & 1], Brow, 256, 128, (ti + 1) * 64)
    }
    __builtin_amdgcn_sched_barrier(0);
    MFMA_BODY(As[ti & 1], Bs[ti & 1], 4, 64)
    __syncthreads();
  }

  const int m = (bx * 2 + wc) * 16 + m16;
  float b0 = bsi[m] + bsh[m];
  float b1 = bsi[256 + m] + bsh[256 + m];
  float b2 = bsi[512 + m] + bsh[512 + m];
  float b3 = bsi[768 + m] + bsh[768 + m];
#pragma unroll
  for (int i = 0; i < 4; ++i)
#pragma unroll
    for (int r2 = 0; r2 < 4; ++r2) {
      int r = rowBase + wm + i * 16 + q * 4 + r2;
      size_t o = (size_t)r * 256 + m;
      float4 pv = *(const float4*)(PR + o * 4);
      float ii = sigf(acc[i][0][r2] + pv.x + b0);
      float ff = sigf(acc[i][1][r2] + pv.y + b1);
      float gg = tanh_a(acc[i][2][r2] + pv.z + b2);
      float oo = sigf(acc[i][3][r2] + pv.w + b3);
      float c2 = ff * c1[o] + ii * gg;
      HT[o] = f2bf(oo * tanh_a(c2));
    }
}

// ---------------------------------------------------------------------------
// GEMM3 + node-gate epilogue. A = [HT | xbf-slice] (crows x 768 bf16),
// B = WEX2t (gates i,u,o,f). Uses FHL/FHR + children cbuf.
// lvl>0: write cbuf + parent Ain (h bf16, rel). lvl==0: write d_out fp32.
__global__ __launch_bounds__(256) void k_gemm3(
    const unsigned short* __restrict__ HT, const unsigned short* __restrict__ xnode,
    const unsigned short* __restrict__ Bt,
    const float* __restrict__ FHL, const float* __restrict__ FHR,
    float* __restrict__ cbuf, unsigned short* __restrict__ Ain,
    const float* __restrict__ rel, float* __restrict__ out,
    const float* __restrict__ bix, const float* __restrict__ bih,
    const float* __restrict__ bux, const float* __restrict__ buh,
    const float* __restrict__ box, const float* __restrict__ boh,
    const float* __restrict__ bfx, const float* __restrict__ bfh,
    int base, int v0, int n, int lvl) {
  __shared__ alignas(16) unsigned short As[2][128 * 64];
  __shared__ alignas(16) unsigned short Bs[2][128 * 64];
  int bx, by; swz_blk(bx, by);
  const int t = threadIdx.x;
  const int wave = t >> 6, lane = t & 63;
  const int wm = (wave & 1) * 64, wc = wave >> 1;
  const int m16 = lane & 15, q = lane >> 4;
  const int l8 = lane >> 3, l7 = lane & 7;
  const int gsw = ((l7 ^ l8) * 8);
  const int rowBase = by * 128;
  const unsigned short* Brow = Bt + (size_t)bx * 128 * 768;
  f32x4 acc[4][4] = {};

  // A source: k<256 from HT (stride 256), k>=256 from xnode (stride 512).
  auto stageA = [&](unsigned short* dst, int kb) {
    if (kb < 256) {
      const unsigned short* Arow = HT + (size_t)rowBase * 256;
#pragma unroll
      for (int c = 0; c < 4; ++c) {
        int row8 = wave * 32 + c * 8;
        load16_lds(Arow + (size_t)(row8 + l8) * 256 + kb + gsw, &dst[row8 * 64]);
      }
    } else {
      const unsigned short* Arow = xnode + (size_t)rowBase * 512;
      int k0 = kb - 256;
#pragma unroll
      for (int c = 0; c < 4; ++c) {
        int row8 = wave * 32 + c * 8;
        load16_lds(Arow + (size_t)(row8 + l8) * 512 + k0 + gsw, &dst[row8 * 64]);
      }
    }
  };

  stageA(As[0], 0);
  STAGE(Bs[0], Brow, 768, 128, 0)
  __syncthreads();
#pragma unroll
  for (int ti = 0; ti < 12; ++ti) {
    if (ti < 11) {
      stageA(As[(ti + 1) & 1], (ti + 1) * 64);
      STAGE(Bs[(ti + 1) & 1], Brow, 768, 128, (ti + 1) * 64)
    }
    __builtin_amdgcn_sched_barrier(0);
    MFMA_BODY(As[ti & 1], Bs[ti & 1], 4, 64)
    __syncthreads();
  }

  const int m = (bx * 2 + wc) * 16 + m16;
  float bi = bix[m] + bih[m];
  float bu = bux[m] + buh[m];
  float bo = box[m] + boh[m];
  float bf = bfx[m] + bfh[m];
#pragma unroll
  for (int i = 0; i < 4; ++i)
#pragma unroll
    for (int r2 = 0; r2 < 4; ++r2) {
      int r = rowBase + wm + i * 16 + q * 4 + r2;
      int vloc = r >> 7, b = r & 127;
      int vg = v0 + vloc;
      int node = base + vg;
      int ch0 = 2 * node + 1;
      size_t o = (size_t)r * 256 + m;
      float pf = acc[i][3][r2] + bf;
      float f0 = sigf(pf + FHL[o]);
      float f1 = sigf(pf + FHR[o]);
      float ii = sigf(acc[i][0][r2] + bi);
      float uu = tanh_a(acc[i][1][r2] + bu);
      float oo = sigf(acc[i][2][r2] + bo);
      float cc = ii * uu + f0 * cbuf[((size_t)ch0 * 128 + b) * 256 + m]
                         + f1 * cbuf[((size_t)(ch0 + 1) * 128 + b) * 256 + m];
      float hh = oo * tanh_a(cc);
      if (lvl == 0) {
        out[b * 256 + m] = hh;
      } else {
        cbuf[((size_t)node * 128 + b) * 256 + m] = cc;
        int rowA = (vg & 1) * (n >> 1) * 128 + (vg >> 1) * 128 + b;
        Ain[(size_t)rowA * 320 + m] = f2bf(hh);
        if (m < 64)
          Ain[(size_t)rowA * 320 + 256 + m] = f2bf(rel[((size_t)b * NNODE + node) * 64 + m]);
      }
    }
}

// ---------------------------------------------------------------------------
// Leaf GEMM + epilogue. A = xbf leaf slice (32768 x 512 bf16), B = WL2t
// (gates i,u,o). c = i*u; writes cbuf + level-7 Ain.
__global__ __launch_bounds__(256) void k_leaf(
    const unsigned short* __restrict__ xleaf, const unsigned short* __restrict__ Bt,
    float* __restrict__ cbuf, unsigned short* __restrict__ Ain,
    const float* __restrict__ rel,
    const float* __restrict__ bix, const float* __restrict__ bih,
    const float* __restrict__ bux, const float* __restrict__ buh,
    const float* __restrict__ box, const float* __restrict__ boh) {
  __shared__ alignas(16) unsigned short As[2][128 * 64];
  __shared__ alignas(16) unsigned short Bs[2][96 * 64];
  int bx, by; swz_blk(bx, by);
  const int t = threadIdx.x;
  const int wave = t >> 6, lane = t & 63;
  const int wm = (wave & 1) * 64, wc = wave >> 1;
  const int m16 = lane & 15, q = lane >> 4;
  const int l8 = lane >> 3, l7 = lane & 7;
  const int gsw = ((l7 ^ l8) * 8);
  const int rowBase = by * 128;
  const unsigned short* Arow = xleaf + (size_t)rowBase * 512;
  const unsigned short* Brow = Bt + (size_t)bx * 96 * 512;
  f32x4 acc[4][3] = {};

  STAGE(As[0], Arow, 512, 128, 0)
#pragma unroll
  for (int c = 0; c < 3; ++c) {
    int row8 = wave * 24 + c * 8;
    load16_lds(Brow + (size_t)(row8 + l8) * 512 + 0 + gsw, &Bs[0][row8 * 64]);
  }
  __syncthreads();
#pragma unroll
  for (int ti = 0; ti < 8; ++ti) {
    if (ti < 7) {
      int kn = (ti + 1) * 64;
      STAGE(As[(ti + 1) & 1], Arow, 512, 128, kn)
#pragma unroll
      for (int c = 0; c < 3; ++c) {
        int row8 = wave * 24 + c * 8;
        load16_lds(Brow + (size_t)(row8 + l8) * 512 + kn + gsw, &Bs[(ti + 1) & 1][row8 * 64]);
      }
    }
    __builtin_amdgcn_sched_barrier(0);
    MFMA_BODY(As[ti & 1], Bs[ti & 1], 3, 48)
    __syncthreads();
  }

  const int m = (bx * 2 + wc) * 16 + m16;
  float bi = bix[m] + bih[m];
  float bu = bux[m] + buh[m];
  float bo = box[m] + boh[m];
#pragma unroll
  for (int i = 0; i < 4; ++i)
#pragma unroll
    for (int r2 = 0; r2 < 4; ++r2) {
      int r = rowBase + wm + i * 16 + q * 4 + r2;
      int vg = r >> 7, b = r & 127;
      int node = 255 + vg;
      float ii = sigf(acc[i][0][r2] + bi);
      float uu = tanh_a(acc[i][1][r2] + bu);
      float oo = sigf(acc[i][2][r2] + bo);
      float cc = ii * uu;
      float hh = oo * tanh_a(cc);
      cbuf[((size_t)node * 128 + b) * 256 + m] = cc;
      int rowA = (vg & 1) * 16384 + (vg >> 1) * 128 + b;
      Ain[(size_t)rowA * 320 + m] = f2bf(hh);
      if (m < 64)
        Ain[(size_t)rowA * 320 + 256 + m] = f2bf(rel[((size_t)b * NNODE + node) * 64 + m]);
    }
}

// ---------------------------------------------------------------------------
extern "C" void kernel_launch(void* const* d_in, const int* in_sizes, int n_in,
                              void* d_out, int out_size, void* d_ws, size_t ws_size,
                              hipStream_t stream) {
  const float* wte = (const float*)d_in[0];
  const float* rel = (const float*)d_in[1];
  const float* Wix = (const float*)d_in[3];
  const float* bix = (const float*)d_in[4];
  const float* Wfx = (const float*)d_in[5];
  const float* bfx = (const float*)d_in[6];
  const float* Wux = (const float*)d_in[7];
  const float* bux = (const float*)d_in[8];
  const float* Wox = (const float*)d_in[9];
  const float* box = (const float*)d_in[10];
  const float* Wih = (const float*)d_in[11];
  const float* bih = (const float*)d_in[12];
  const float* Wfh = (const float*)d_in[13];
  const float* bfh = (const float*)d_in[14];
  const float* Wuh = (const float*)d_in[15];
  const float* buh = (const float*)d_in[16];
  const float* Woh = (const float*)d_in[17];
  const float* boh = (const float*)d_in[18];
  const float* Wsi = (const float*)d_in[19];
  const float* Wsh = (const float*)d_in[20];
  const float* bsi = (const float*)d_in[21];
  const float* bsh = (const float*)d_in[22];
  float* out = (float*)d_out;
  (void)in_sizes; (void)n_in; (void)out_size;

  int INT_MAXN;
  if (ws_size >= (size_t)310 * 1024 * 1024)      INT_MAXN = 128;
  else if (ws_size >= (size_t)200 * 1024 * 1024) INT_MAXN = 32;
  else                                           INT_MAXN = 8;
  const int crowsMax = INT_MAXN * 128;

  char* ws = (char*)d_ws;
  size_t off = 0;
  auto alloc = [&](size_t bytes) {
    size_t o = off; off += (bytes + 255) & ~(size_t)255; return o;
  };
  unsigned short* xbf  = (unsigned short*)(ws + alloc((size_t)NNODE * 128 * 512 * 2));
  float*          cbuf = (float*)         (ws + alloc((size_t)NNODE * 128 * 256 * 4));
  unsigned short* Ain  = (unsigned short*)(ws + alloc((size_t)32768 * 320 * 2));
  unsigned short* WL2t = (unsigned short*)(ws + alloc((size_t)768 * 512 * 2));
  unsigned short* WA2t = (unsigned short*)(ws + alloc((size_t)1280 * 320 * 2));
  unsigned short* WH2t = (unsigned short*)(ws + alloc((size_t)1024 * 256 * 2));
  unsigned short* WEX2t= (unsigned short*)(ws + alloc((size_t)1024 * 768 * 2));
  unsigned short* h1   = (unsigned short*)(ws + alloc((size_t)crowsMax * 256 * 2));
  float*          c1   = (float*)         (ws + alloc((size_t)crowsMax * 256 * 4));
  float*          FHL  = (float*)         (ws + alloc((size_t)crowsMax * 256 * 4));
  float*          FHR  = (float*)         (ws + alloc((size_t)crowsMax * 256 * 4));
  float*          PR   = (float*)         (ws + alloc((size_t)crowsMax * 1024 * 4));
  unsigned short* HT   = (unsigned short*)(ws + alloc((size_t)crowsMax * 256 * 2));

  k_prep_x<<<32704, 256, 0, stream>>>(wte, xbf);
  k_prep_w<<<7232, 256, 0, stream>>>(Wix, Wux, Wox, Wfx, Wih, Wuh, Woh, Wfh,
                                     Wsi, Wsh, WL2t, WA2t, WH2t, WEX2t);

  // Leaves: one fused GEMM over xbf rows [255*128, 511*128).
  k_leaf<<<dim3(8, 256), 256, 0, stream>>>(xbf + (size_t)255 * 128 * 512, WL2t,
                                           cbuf, Ain, rel, bix, bih, bux, buh, box, boh);

  // Internal levels 7..0, 3 fused launches per chunk.
  for (int lvl = 7; lvl >= 0; --lvl) {
    int n = 1 << lvl;
    int base = n - 1;
    int cn = (n < INT_MAXN) ? n : INT_MAXN;
    for (int v0 = 0; v0 < n; v0 += cn) {
      int crows = cn * 128;
      const unsigned short* AinL = Ain + (size_t)(v0 * 128) * 320;
      const unsigned short* AinR = Ain + (size_t)((n + v0) * 128) * 320;
      const unsigned short* xnode = xbf + (size_t)(base + v0) * 128 * 512;
      k_gemm1<<<dim3(8, 2 * cn), 256, 0, stream>>>(AinL, AinR, WA2t, h1, c1,
                                                   FHL, FHR, PR, bsi, bsh, crows);
      k_gemm2<<<dim3(8, cn), 256, 0, stream>>>(h1, WH2t, PR, c1, HT, bsi, bsh);
      k_gemm3<<<dim3(8, cn), 256, 0, stream>>>(HT, xnode, WEX2t, FHL, FHR, cbuf, Ain,
                                               rel, out, bix, bih, bux, buh, box, boh,
                                               bfx, bfh, base, v0, n, lvl);
    }
  }
}

// Round 3
// 785.096 us; speedup vs baseline: 1.3095x; 1.0045x over previous
//
#include <hip/hip_runtime.h>
#include <math.h>

// N=511 complete binary tree: nodes 0..254 internal (both children valid),
// 255..510 leaves. B=128, M=256, IN=512, R=64.
// Gate-interleaved bf16 weight layouts fuse every LSTM-cell epilogue into its
// producing GEMM. GEMM staging uses global_load_lds width=16 (async direct-to-
// LDS). LDS tiles are unpadded (stride 64 shorts) with an XOR k-slot swizzle
// compensated in the per-lane global source address (ds_read_b128 conflict-free).
// Round 5: fast exp2/rcp transcendentals + XCD block remap (VALU 33->14%).
// Round 6: 2-phase double-buffered K-loop -- NEUTRAL on gemm3 (MfmaUtil 12.3->
// 12.6): __syncthreads() drains vmcnt(0), serializing on the just-issued
// prefetch (T3-without-T4 null, m218).
// Round 7: T4 counted vmcnt. STAGE(t+1) -> s_waitcnt vmcnt(N) (drains only
// buf[t]'s loads, issued a full step earlier) -> raw s_barrier -> MFMA ->
// raw s_barrier (WAR guard). Prefetch stays in flight across the whole step.
#define NNODE 511

typedef short s16x8 __attribute__((ext_vector_type(8)));
typedef float f32x4 __attribute__((ext_vector_type(4)));

__device__ __forceinline__ unsigned short f2bf(float f) {
  unsigned int u = __builtin_bit_cast(unsigned int, f);
  u += 0x7fffu + ((u >> 16) & 1u);           // RNE
  return (unsigned short)(u >> 16);
}
// Fast sigmoid/tanh via v_exp_f32 (2^x) + v_rcp_f32. ~1 ulp vs libm; exact
// saturation at +-inf (rcp(inf)=0).
__device__ __forceinline__ float sigf(float x) {
  float e = __builtin_amdgcn_exp2f(-1.442695040888963f * x);
  return __builtin_amdgcn_rcpf(1.0f + e);
}
__device__ __forceinline__ float tanh_a(float x) {
  float e = __builtin_amdgcn_exp2f(2.885390081777927f * x);
  return 1.0f - 2.0f * __builtin_amdgcn_rcpf(1.0f + e);
}

__device__ __forceinline__ void load16_lds(const unsigned short* g, unsigned short* l) {
  __builtin_amdgcn_global_load_lds(
      (const __attribute__((address_space(1))) void*)g,
      (__attribute__((address_space(3))) void*)l, 16, 0, 0);
}

// Counted vmcnt drain: wait until at most N VMEM ops outstanding. "memory"
// clobber fences compiler reordering of LDS reads/stores across it.
template<int N> __device__ __forceinline__ void s_wait_vmcnt() {
  asm volatile("s_waitcnt vmcnt(%0)" :: "n"(N) : "memory");
}

// XCD-aware block remap. Grid is always (8, ny). Remap so XCD k owns a
// contiguous by-range x all bx (bijective when ny%8==0; tail launches L2-fit).
__device__ __forceinline__ void swz_blk(int& bx, int& by) {
  bx = blockIdx.x; by = blockIdx.y;
  int ny = gridDim.y;
  if ((ny & 7) == 0) {
    int lin = by * 8 + bx;
    int w = lin >> 3;
    by = (lin & 7) * (ny >> 3) + (w >> 3);
    bx = w & 7;
  }
}

// ---------------------------------------------------------------------------
// wte (B,511,512) fp32 -> xbf (node,b,k) bf16, node-major. One-time.
__global__ void k_prep_x(const float* __restrict__ w, unsigned short* __restrict__ xbf) {
  int o = (blockIdx.x * 256 + threadIdx.x) * 4;   // out elem: node*65536 + b*512 + k
  int node = o >> 16;
  int b = (o >> 9) & 127;
  int k = o & 511;
  const float4 v = *(const float4*)(w + ((size_t)b * NNODE + node) * 512 + k);
  unsigned int p0 = (unsigned int)f2bf(v.x) | ((unsigned int)f2bf(v.y) << 16);
  unsigned int p1 = (unsigned int)f2bf(v.z) | ((unsigned int)f2bf(v.w) << 16);
  *(uint2*)(xbf + o) = make_uint2(p0, p1);
}

// ---------------------------------------------------------------------------
// Gate-interleaved transposed weights (c = column index, k = reduction index):
//  WL2t (768,512):  c = 48G+16g+mi, g in {i,u,o}
//  WA2t (1280,320): c = 80G+16g+mi, g in {i,f,g,o,fh}
//  WH2t (1024,256): c = 64G+16g+mi, g in {i,f,g,o}
//  WEX2t(1024,768): c = 64G+16g+mi, g in {i,u,o,f}; k<256 h-weights, k>=256 x-weights
__global__ void k_prep_w(const float* __restrict__ Wix, const float* __restrict__ Wux,
                         const float* __restrict__ Wox, const float* __restrict__ Wfx,
                         const float* __restrict__ Wih, const float* __restrict__ Wuh,
                         const float* __restrict__ Woh, const float* __restrict__ Wfh,
                         const float* __restrict__ Wsi, const float* __restrict__ Wsh,
                         unsigned short* __restrict__ WL2t, unsigned short* __restrict__ WA2t,
                         unsigned short* __restrict__ WH2t, unsigned short* __restrict__ WEX2t) {
  int idx = blockIdx.x * 256 + threadIdx.x;
  if (idx < 393216) {                       // WL2t 768*512
    int c = idx >> 9, k = idx & 511;
    int G = c / 48, rem = c - G * 48, g = rem >> 4, mi = rem & 15, m = G * 16 + mi;
    const float* W = (g == 0) ? Wix : (g == 1) ? Wux : Wox;
    WL2t[idx] = f2bf(W[k * 256 + m]);
  } else if (idx < 802816) {                // WA2t 1280*320
    int o = idx - 393216;
    int c = o / 320, k = o - c * 320;
    int G = c / 80, rem = c - G * 80, g = rem >> 4, mi = rem & 15, m = G * 16 + mi;
    float v;
    if (g < 4) v = Wsi[k * 1024 + g * 256 + m];
    else       v = (k < 256) ? Wfh[k * 256 + m] : 0.0f;
    WA2t[o] = f2bf(v);
  } else if (idx < 1064960) {               // WH2t 1024*256
    int o = idx - 802816;
    int c = o >> 8, k = o & 255;
    int G = c >> 6, rem = c & 63, g = rem >> 4, mi = rem & 15, m = G * 16 + mi;
    WH2t[o] = f2bf(Wsh[k * 1024 + g * 256 + m]);
  } else if (idx < 1851392) {               // WEX2t 1024*768
    int o = idx - 1064960;
    int c = o / 768, k = o - c * 768;
    int G = c >> 6, rem = c & 63, g = rem >> 4, mi = rem & 15, m = G * 16 + mi;
    float v;
    if (k < 256) {
      v = (g == 0) ? Wih[k * 256 + m] : (g == 1) ? Wuh[k * 256 + m]
        : (g == 2) ? Woh[k * 256 + m] : 0.0f;
    } else {
      int k2 = k - 256;
      v = (g == 0) ? Wix[k2 * 256 + m] : (g == 1) ? Wux[k2 * 256 + m]
        : (g == 2) ? Wox[k2 * 256 + m] : Wfx[k2 * 256 + m];
    }
    WEX2t[o] = f2bf(v);
  }
}

// Swizzled MFMA inner step reading buffers AP/BP. LDS row stride 64 shorts;
// k-slot XOR swizzle. sw(kk) = (kk | q*8) ^ ((m16&7)*8).
#define MFMA_BODY(AP, BP, NG, CW)                                             \
  _Pragma("unroll")                                                           \
  for (int kk = 0; kk < 64; kk += 32) {                                       \
    const int sw = (kk | (q * 8)) ^ ((m16 & 7) * 8);                          \
    s16x8 af[4], bfr[NG];                                                     \
    _Pragma("unroll")                                                         \
    for (int i = 0; i < 4; ++i)                                               \
      af[i] = *(const s16x8*)(&(AP)[(wm + i * 16 + m16) * 64 + sw]);          \
    _Pragma("unroll")                                                         \
    for (int j = 0; j < NG; ++j)                                              \
      bfr[j] = *(const s16x8*)(&(BP)[(wc * CW + j * 16 + m16) * 64 + sw]);    \
    _Pragma("unroll")                                                         \
    for (int i = 0; i < 4; ++i)                                               \
      _Pragma("unroll")                                                       \
      for (int j = 0; j < NG; ++j)                                            \
        acc[i][j] = __builtin_amdgcn_mfma_f32_16x16x32_bf16(af[i], bfr[j], acc[i][j], 0, 0, 0); \
  }

// Stage R rows x 64 shorts from SRC (row stride STRIDE shorts, k offset K0)
// into DST via global_load_lds. Wave w covers rows [w*R/4,(w+1)*R/4).
#define STAGE(DST, SRC, STRIDE, R, K0)                                        \
  _Pragma("unroll")                                                           \
  for (int c = 0; c < (R) / 32; ++c) {                                        \
    int row8 = wave * ((R) / 4) + c * 8;                                      \
    load16_lds(SRC + (size_t)(row8 + l8) * (STRIDE) + (K0) + gsw, &(DST)[row8 * 64]); \
  }

// K-step sync: drain all but the VM newest loads (buf[t]'s loads were issued
// a full step ago; the VM just-issued prefetch stays in flight), barrier,
// pin schedule. Post-MFMA raw barrier guards WAR on buffer reuse.
#define STEP_SYNC(VM)                                                         \
  s_wait_vmcnt<VM>();                                                         \
  __builtin_amdgcn_s_barrier();                                               \
  __builtin_amdgcn_sched_barrier(0);

// ---------------------------------------------------------------------------
// GEMM1 + cell1 epilogue. A = [AinL ; AinR] (2*crows x 320 bf16), B = WA2t.
// L rows -> h1 (bf16), c1, FHL.  R rows -> PR (float4 i,f,g,o preacts), FHR.
__global__ __launch_bounds__(256) void k_gemm1(
    const unsigned short* __restrict__ AinL, const unsigned short* __restrict__ AinR,
    const unsigned short* __restrict__ Bt,
    unsigned short* __restrict__ h1, float* __restrict__ c1,
    float* __restrict__ FHL, float* __restrict__ FHR, float* __restrict__ PR,
    const float* __restrict__ bsi, const float* __restrict__ bsh, int crows) {
  __shared__ alignas(16) unsigned short As[2][128 * 64];
  __shared__ alignas(16) unsigned short Bs[2][160 * 64];
  int bx, by; swz_blk(bx, by);
  const int t = threadIdx.x;
  const int wave = t >> 6, lane = t & 63;
  const int wm = (wave & 1) * 64, wc = wave >> 1;
  const int m16 = lane & 15, q = lane >> 4;
  const int l8 = lane >> 3, l7 = lane & 7;
  const int gsw = ((l7 ^ l8) * 8);
  const int rowBase = by * 128;
  const bool isL = rowBase < crows;
  const unsigned short* Arow = isL ? (AinL + (size_t)rowBase * 320)
                                   : (AinR + (size_t)(rowBase - crows) * 320);
  const unsigned short* Brow = Bt + (size_t)bx * 160 * 320;
  f32x4 acc[4][5] = {};

  STAGE(As[0], Arow, 320, 128, 0)
  STAGE(Bs[0], Brow, 320, 160, 0)
#pragma unroll
  for (int ti = 0; ti < 5; ++ti) {
    if (ti < 4) {
      STAGE(As[(ti + 1) & 1], Arow, 320, 128, (ti + 1) * 64)
      STAGE(Bs[(ti + 1) & 1], Brow, 320, 160, (ti + 1) * 64)
      STEP_SYNC(9)
    } else {
      STEP_SYNC(0)
    }
    MFMA_BODY(As[ti & 1], Bs[ti & 1], 5, 80)
    __builtin_amdgcn_s_barrier();
  }

  const int m = (bx * 2 + wc) * 16 + m16;
  if (isL) {
    float bi = bsi[m] + bsh[m];
    float bg = bsi[512 + m] + bsh[512 + m];
    float bo = bsi[768 + m] + bsh[768 + m];
#pragma unroll
    for (int i = 0; i < 4; ++i)
#pragma unroll
      for (int r2 = 0; r2 < 4; ++r2) {
        int r = rowBase + wm + i * 16 + q * 4 + r2;
        float ii = sigf(acc[i][0][r2] + bi);
        float gg = tanh_a(acc[i][2][r2] + bg);
        float oo = sigf(acc[i][3][r2] + bo);
        float cv = ii * gg;
        size_t o = (size_t)r * 256 + m;
        h1[o] = f2bf(oo * tanh_a(cv));
        c1[o] = cv;
        FHL[o] = acc[i][4][r2];
      }
  } else {
#pragma unroll
    for (int i = 0; i < 4; ++i)
#pragma unroll
      for (int r2 = 0; r2 < 4; ++r2) {
        int rr = rowBase - crows + wm + i * 16 + q * 4 + r2;
        size_t o = (size_t)rr * 256 + m;
        float4 pv = {acc[i][0][r2], acc[i][1][r2], acc[i][2][r2], acc[i][3][r2]};
        *(float4*)(PR + o * 4) = pv;
        FHR[o] = acc[i][4][r2];
      }
  }
}

// ---------------------------------------------------------------------------
// GEMM2 + cell2 epilogue. A = h1 (crows x 256), B = WH2t.
// g = acc + PR + b_seq; h_tilde -> HT (bf16).
__global__ __launch_bounds__(256) void k_gemm2(
    const unsigned short* __restrict__ A, const unsigned short* __restrict__ Bt,
    const float* __restrict__ PR, const float* __restrict__ c1,
    unsigned short* __restrict__ HT,
    const float* __restrict__ bsi, const float* __restrict__ bsh) {
  __shared__ alignas(16) unsigned short As[2][128 * 64];
  __shared__ alignas(16) unsigned short Bs[2][128 * 64];
  int bx, by; swz_blk(bx, by);
  const int t = threadIdx.x;
  const int wave = t >> 6, lane = t & 63;
  const int wm = (wave & 1) * 64, wc = wave >> 1;
  const int m16 = lane & 15, q = lane >> 4;
  const int l8 = lane >> 3, l7 = lane & 7;
  const int gsw = ((l7 ^ l8) * 8);
  const int rowBase = by * 128;
  const unsigned short* Arow = A + (size_t)rowBase * 256;
  const unsigned short* Brow = Bt + (size_t)bx * 128 * 256;
  f32x4 acc[4][4] = {};

  STAGE(As[0], Arow, 256, 128, 0)
  STAGE(Bs[0], Brow, 256, 128, 0)
#pragma unroll
  for (int ti = 0; ti < 4; ++ti) {
    if (ti < 3) {
      STAGE(As[(ti + 1) & 1], Arow, 256, 128, (ti + 1) * 64)
      STAGE(Bs[(ti + 1) & 1], Brow, 256, 128, (ti + 1) * 64)
      STEP_SYNC(8)
    } else {
      STEP_SYNC(0)
    }
    MFMA_BODY(As[ti & 1], Bs[ti & 1], 4, 64)
    __builtin_amdgcn_s_barrier();
  }

  const int m = (bx * 2 + wc) * 16 + m16;
  float b0 = bsi[m] + bsh[m];
  float b1 = bsi[256 + m] + bsh[256 + m];
  float b2 = bsi[512 + m] + bsh[512 + m];
  float b3 = bsi[768 + m] + bsh[768 + m];
#pragma unroll
  for (int i = 0; i < 4; ++i)
#pragma unroll
    for (int r2 = 0; r2 < 4; ++r2) {
      int r = rowBase + wm + i * 16 + q * 4 + r2;
      size_t o = (size_t)r * 256 + m;
      float4 pv = *(const float4*)(PR + o * 4);
      float ii = sigf(acc[i][0][r2] + pv.x + b0);
      float ff = sigf(acc[i][1][r2] + pv.y + b1);
      float gg = tanh_a(acc[i][2][r2] + pv.z + b2);
      float oo = sigf(acc[i][3][r2] + pv.w + b3);
      float c2 = ff * c1[o] + ii * gg;
      HT[o] = f2bf(oo * tanh_a(c2));
    }
}

// ---------------------------------------------------------------------------
// GEMM3 + node-gate epilogue. A = [HT | xbf-slice] (crows x 768 bf16),
// B = WEX2t (gates i,u,o,f). Uses FHL/FHR + children cbuf.
// lvl>0: write cbuf + parent Ain (h bf16, rel). lvl==0: write d_out fp32.
__global__ __launch_bounds__(256) void k_gemm3(
    const unsigned short* __restrict__ HT, const unsigned short* __restrict__ xnode,
    const unsigned short* __restrict__ Bt,
    const float* __restrict__ FHL, const float* __restrict__ FHR,
    float* __restrict__ cbuf, unsigned short* __restrict__ Ain,
    const float* __restrict__ rel, float* __restrict__ out,
    const float* __restrict__ bix, const float* __restrict__ bih,
    const float* __restrict__ bux, const float* __restrict__ buh,
    const float* __restrict__ box, const float* __restrict__ boh,
    const float* __restrict__ bfx, const float* __restrict__ bfh,
    int base, int v0, int n, int lvl) {
  __shared__ alignas(16) unsigned short As[2][128 * 64];
  __shared__ alignas(16) unsigned short Bs[2][128 * 64];
  int bx, by; swz_blk(bx, by);
  const int t = threadIdx.x;
  const int wave = t >> 6, lane = t & 63;
  const int wm = (wave & 1) * 64, wc = wave >> 1;
  const int m16 = lane & 15, q = lane >> 4;
  const int l8 = lane >> 3, l7 = lane & 7;
  const int gsw = ((l7 ^ l8) * 8);
  const int rowBase = by * 128;
  const unsigned short* Brow = Bt + (size_t)bx * 128 * 768;
  f32x4 acc[4][4] = {};

  // A source: k<256 from HT (stride 256), k>=256 from xnode (stride 512).
  auto stageA = [&](unsigned short* dst, int kb) {
    if (kb < 256) {
      const unsigned short* Arow = HT + (size_t)rowBase * 256;
#pragma unroll
      for (int c = 0; c < 4; ++c) {
        int row8 = wave * 32 + c * 8;
        load16_lds(Arow + (size_t)(row8 + l8) * 256 + kb + gsw, &dst[row8 * 64]);
      }
    } else {
      const unsigned short* Arow = xnode + (size_t)rowBase * 512;
      int k0 = kb - 256;
#pragma unroll
      for (int c = 0; c < 4; ++c) {
        int row8 = wave * 32 + c * 8;
        load16_lds(Arow + (size_t)(row8 + l8) * 512 + k0 + gsw, &dst[row8 * 64]);
      }
    }
  };

  stageA(As[0], 0);
  STAGE(Bs[0], Brow, 768, 128, 0)
#pragma unroll
  for (int ti = 0; ti < 12; ++ti) {
    if (ti < 11) {
      stageA(As[(ti + 1) & 1], (ti + 1) * 64);
      STAGE(Bs[(ti + 1) & 1], Brow, 768, 128, (ti + 1) * 64)
      STEP_SYNC(8)
    } else {
      STEP_SYNC(0)
    }
    MFMA_BODY(As[ti & 1], Bs[ti & 1], 4, 64)
    __builtin_amdgcn_s_barrier();
  }

  const int m = (bx * 2 + wc) * 16 + m16;
  float bi = bix[m] + bih[m];
  float bu = bux[m] + buh[m];
  float bo = box[m] + boh[m];
  float bf = bfx[m] + bfh[m];
#pragma unroll
  for (int i = 0; i < 4; ++i)
#pragma unroll
    for (int r2 = 0; r2 < 4; ++r2) {
      int r = rowBase + wm + i * 16 + q * 4 + r2;
      int vloc = r >> 7, b = r & 127;
      int vg = v0 + vloc;
      int node = base + vg;
      int ch0 = 2 * node + 1;
      size_t o = (size_t)r * 256 + m;
      float pf = acc[i][3][r2] + bf;
      float f0 = sigf(pf + FHL[o]);
      float f1 = sigf(pf + FHR[o]);
      float ii = sigf(acc[i][0][r2] + bi);
      float uu = tanh_a(acc[i][1][r2] + bu);
      float oo = sigf(acc[i][2][r2] + bo);
      float cc = ii * uu + f0 * cbuf[((size_t)ch0 * 128 + b) * 256 + m]
                         + f1 * cbuf[((size_t)(ch0 + 1) * 128 + b) * 256 + m];
      float hh = oo * tanh_a(cc);
      if (lvl == 0) {
        out[b * 256 + m] = hh;
      } else {
        cbuf[((size_t)node * 128 + b) * 256 + m] = cc;
        int rowA = (vg & 1) * (n >> 1) * 128 + (vg >> 1) * 128 + b;
        Ain[(size_t)rowA * 320 + m] = f2bf(hh);
        if (m < 64)
          Ain[(size_t)rowA * 320 + 256 + m] = f2bf(rel[((size_t)b * NNODE + node) * 64 + m]);
      }
    }
}

// ---------------------------------------------------------------------------
// Leaf GEMM + epilogue. A = xbf leaf slice (32768 x 512 bf16), B = WL2t
// (gates i,u,o). c = i*u; writes cbuf + level-7 Ain.
__global__ __launch_bounds__(256) void k_leaf(
    const unsigned short* __restrict__ xleaf, const unsigned short* __restrict__ Bt,
    float* __restrict__ cbuf, unsigned short* __restrict__ Ain,
    const float* __restrict__ rel,
    const float* __restrict__ bix, const float* __restrict__ bih,
    const float* __restrict__ bux, const float* __restrict__ buh,
    const float* __restrict__ box, const float* __restrict__ boh) {
  __shared__ alignas(16) unsigned short As[2][128 * 64];
  __shared__ alignas(16) unsigned short Bs[2][96 * 64];
  int bx, by; swz_blk(bx, by);
  const int t = threadIdx.x;
  const int wave = t >> 6, lane = t & 63;
  const int wm = (wave & 1) * 64, wc = wave >> 1;
  const int m16 = lane & 15, q = lane >> 4;
  const int l8 = lane >> 3, l7 = lane & 7;
  const int gsw = ((l7 ^ l8) * 8);
  const int rowBase = by * 128;
  const unsigned short* Arow = xleaf + (size_t)rowBase * 512;
  const unsigned short* Brow = Bt + (size_t)bx * 96 * 512;
  f32x4 acc[4][3] = {};

  STAGE(As[0], Arow, 512, 128, 0)
#pragma unroll
  for (int c = 0; c < 3; ++c) {
    int row8 = wave * 24 + c * 8;
    load16_lds(Brow + (size_t)(row8 + l8) * 512 + 0 + gsw, &Bs[0][row8 * 64]);
  }
#pragma unroll
  for (int ti = 0; ti < 8; ++ti) {
    if (ti < 7) {
      int kn = (ti + 1) * 64;
      STAGE(As[(ti + 1) & 1], Arow, 512, 128, kn)
#pragma unroll
      for (int c = 0; c < 3; ++c) {
        int row8 = wave * 24 + c * 8;
        load16_lds(Brow + (size_t)(row8 + l8) * 512 + kn + gsw, &Bs[(ti + 1) & 1][row8 * 64]);
      }
      STEP_SYNC(7)
    } else {
      STEP_SYNC(0)
    }
    MFMA_BODY(As[ti & 1], Bs[ti & 1], 3, 48)
    __builtin_amdgcn_s_barrier();
  }

  const int m = (bx * 2 + wc) * 16 + m16;
  float bi = bix[m] + bih[m];
  float bu = bux[m] + buh[m];
  float bo = box[m] + boh[m];
#pragma unroll
  for (int i = 0; i < 4; ++i)
#pragma unroll
    for (int r2 = 0; r2 < 4; ++r2) {
      int r = rowBase + wm + i * 16 + q * 4 + r2;
      int vg = r >> 7, b = r & 127;
      int node = 255 + vg;
      float ii = sigf(acc[i][0][r2] + bi);
      float uu = tanh_a(acc[i][1][r2] + bu);
      float oo = sigf(acc[i][2][r2] + bo);
      float cc = ii * uu;
      float hh = oo * tanh_a(cc);
      cbuf[((size_t)node * 128 + b) * 256 + m] = cc;
      int rowA = (vg & 1) * 16384 + (vg >> 1) * 128 + b;
      Ain[(size_t)rowA * 320 + m] = f2bf(hh);
      if (m < 64)
        Ain[(size_t)rowA * 320 + 256 + m] = f2bf(rel[((size_t)b * NNODE + node) * 64 + m]);
    }
}

// ---------------------------------------------------------------------------
extern "C" void kernel_launch(void* const* d_in, const int* in_sizes, int n_in,
                              void* d_out, int out_size, void* d_ws, size_t ws_size,
                              hipStream_t stream) {
  const float* wte = (const float*)d_in[0];
  const float* rel = (const float*)d_in[1];
  const float* Wix = (const float*)d_in[3];
  const float* bix = (const float*)d_in[4];
  const float* Wfx = (const float*)d_in[5];
  const float* bfx = (const float*)d_in[6];
  const float* Wux = (const float*)d_in[7];
  const float* bux = (const float*)d_in[8];
  const float* Wox = (const float*)d_in[9];
  const float* box = (const float*)d_in[10];
  const float* Wih = (const float*)d_in[11];
  const float* bih = (const float*)d_in[12];
  const float* Wfh = (const float*)d_in[13];
  const float* bfh = (const float*)d_in[14];
  const float* Wuh = (const float*)d_in[15];
  const float* buh = (const float*)d_in[16];
  const float* Woh = (const float*)d_in[17];
  const float* boh = (const float*)d_in[18];
  const float* Wsi = (const float*)d_in[19];
  const float* Wsh = (const float*)d_in[20];
  const float* bsi = (const float*)d_in[21];
  const float* bsh = (const float*)d_in[22];
  float* out = (float*)d_out;
  (void)in_sizes; (void)n_in; (void)out_size;

  int INT_MAXN;
  if (ws_size >= (size_t)310 * 1024 * 1024)      INT_MAXN = 128;
  else if (ws_size >= (size_t)200 * 1024 * 1024) INT_MAXN = 32;
  else                                           INT_MAXN = 8;
  const int crowsMax = INT_MAXN * 128;

  char* ws = (char*)d_ws;
  size_t off = 0;
  auto alloc = [&](size_t bytes) {
    size_t o = off; off += (bytes + 255) & ~(size_t)255; return o;
  };
  unsigned short* xbf  = (unsigned short*)(ws + alloc((size_t)NNODE * 128 * 512 * 2));
  float*          cbuf = (float*)         (ws + alloc((size_t)NNODE * 128 * 256 * 4));
  unsigned short* Ain  = (unsigned short*)(ws + alloc((size_t)32768 * 320 * 2));
  unsigned short* WL2t = (unsigned short*)(ws + alloc((size_t)768 * 512 * 2));
  unsigned short* WA2t = (unsigned short*)(ws + alloc((size_t)1280 * 320 * 2));
  unsigned short* WH2t = (unsigned short*)(ws + alloc((size_t)1024 * 256 * 2));
  unsigned short* WEX2t= (unsigned short*)(ws + alloc((size_t)1024 * 768 * 2));
  unsigned short* h1   = (unsigned short*)(ws + alloc((size_t)crowsMax * 256 * 2));
  float*          c1   = (float*)         (ws + alloc((size_t)crowsMax * 256 * 4));
  float*          FHL  = (float*)         (ws + alloc((size_t)crowsMax * 256 * 4));
  float*          FHR  = (float*)         (ws + alloc((size_t)crowsMax * 256 * 4));
  float*          PR   = (float*)         (ws + alloc((size_t)crowsMax * 1024 * 4));
  unsigned short* HT   = (unsigned short*)(ws + alloc((size_t)crowsMax * 256 * 2));

  k_prep_x<<<32704, 256, 0, stream>>>(wte, xbf);
  k_prep_w<<<7232, 256, 0, stream>>>(Wix, Wux, Wox, Wfx, Wih, Wuh, Woh, Wfh,
                                     Wsi, Wsh, WL2t, WA2t, WH2t, WEX2t);

  // Leaves: one fused GEMM over xbf rows [255*128, 511*128).
  k_leaf<<<dim3(8, 256), 256, 0, stream>>>(xbf + (size_t)255 * 128 * 512, WL2t,
                                           cbuf, Ain, rel, bix, bih, bux, buh, box, boh);

  // Internal levels 7..0, 3 fused launches per chunk.
  for (int lvl = 7; lvl >= 0; --lvl) {
    int n = 1 << lvl;
    int base = n - 1;
    int cn = (n < INT_MAXN) ? n : INT_MAXN;
    for (int v0 = 0; v0 < n; v0 += cn) {
      int crows = cn * 128;
      const unsigned short* AinL = Ain + (size_t)(v0 * 128) * 320;
      const unsigned short* AinR = Ain + (size_t)((n + v0) * 128) * 320;
      const unsigned short* xnode = xbf + (size_t)(base + v0) * 128 * 512;
      k_gemm1<<<dim3(8, 2 * cn), 256, 0, stream>>>(AinL, AinR, WA2t, h1, c1,
                                                   FHL, FHR, PR, bsi, bsh, crows);
      k_gemm2<<<dim3(8, cn), 256, 0, stream>>>(h1, WH2t, PR, c1, HT, bsi, bsh);
      k_gemm3<<<dim3(8, cn), 256, 0, stream>>>(HT, xnode, WEX2t, FHL, FHR, cbuf, Ain,
                                               rel, out, bix, bih, bux, buh, box, boh,
                                               bfx, bfh, base, v0, n, lvl);
    }
  }
}

// Round 4
// 744.969 us; speedup vs baseline: 1.3800x; 1.0539x over previous
//
#include <hip/hip_runtime.h>
#include <math.h>

// N=511 complete binary tree: nodes 0..254 internal (both children valid),
// 255..510 leaves. B=128, M=256, IN=512, R=64.
// Gate-interleaved bf16 weight layouts fuse every LSTM-cell epilogue into its
// producing GEMM. GEMM staging uses global_load_lds width=16 (async direct-to-
// LDS). LDS tiles are unpadded (stride 64 shorts) with an XOR k-slot swizzle
// compensated in the per-lane global source address (ds_read_b128 conflict-free).
// Round 5: fast exp2/rcp transcendentals + XCD block remap (VALU 33->14%).
// Round 6/7: dbuf + counted-vmcnt K-loop -- BOTH NULL on gemm3 (77 us pinned,
// MfmaUtil ~12.5-12.9). Conclusion: K-loop was never binding; MFMA busy ==
// floor, K-loop wall ~27 us at typical 37% util => ~50 us is the EPILOGUE:
// 64 serialized scalar fp32 loads/lane (FHL/FHR/cbuf x2) under an 88-VGPR
// budget (allocator can't batch loads; each is a ~900cy HBM hop).
// Round 8: __launch_bounds__(256,2) raises VGPR cap to 256; T14 epilogue
// operand prefetch in gemm2/gemm3 issued under the last two MFMA bodies
// (final drain vmcnt(63)/(32): stage loads are older, prefetch stays in
// flight); bias loads hoisted above the K-loop.
#define NNODE 511

typedef short s16x8 __attribute__((ext_vector_type(8)));
typedef float f32x4 __attribute__((ext_vector_type(4)));

__device__ __forceinline__ unsigned short f2bf(float f) {
  unsigned int u = __builtin_bit_cast(unsigned int, f);
  u += 0x7fffu + ((u >> 16) & 1u);           // RNE
  return (unsigned short)(u >> 16);
}
// Fast sigmoid/tanh via v_exp_f32 (2^x) + v_rcp_f32. ~1 ulp vs libm; exact
// saturation at +-inf (rcp(inf)=0).
__device__ __forceinline__ float sigf(float x) {
  float e = __builtin_amdgcn_exp2f(-1.442695040888963f * x);
  return __builtin_amdgcn_rcpf(1.0f + e);
}
__device__ __forceinline__ float tanh_a(float x) {
  float e = __builtin_amdgcn_exp2f(2.885390081777927f * x);
  return 1.0f - 2.0f * __builtin_amdgcn_rcpf(1.0f + e);
}

__device__ __forceinline__ void load16_lds(const unsigned short* g, unsigned short* l) {
  __builtin_amdgcn_global_load_lds(
      (const __attribute__((address_space(1))) void*)g,
      (__attribute__((address_space(3))) void*)l, 16, 0, 0);
}

// Counted vmcnt drain: wait until at most N VMEM ops outstanding. "memory"
// clobber fences compiler reordering of memory ops across it.
template<int N> __device__ __forceinline__ void s_wait_vmcnt() {
  asm volatile("s_waitcnt vmcnt(%0)" :: "n"(N) : "memory");
}

// XCD-aware block remap. Grid is always (8, ny). Remap so XCD k owns a
// contiguous by-range x all bx (bijective when ny%8==0; tail launches L2-fit).
__device__ __forceinline__ void swz_blk(int& bx, int& by) {
  bx = blockIdx.x; by = blockIdx.y;
  int ny = gridDim.y;
  if ((ny & 7) == 0) {
    int lin = by * 8 + bx;
    int w = lin >> 3;
    by = (lin & 7) * (ny >> 3) + (w >> 3);
    bx = w & 7;
  }
}

// ---------------------------------------------------------------------------
// wte (B,511,512) fp32 -> xbf (node,b,k) bf16, node-major. One-time.
__global__ void k_prep_x(const float* __restrict__ w, unsigned short* __restrict__ xbf) {
  int o = (blockIdx.x * 256 + threadIdx.x) * 4;   // out elem: node*65536 + b*512 + k
  int node = o >> 16;
  int b = (o >> 9) & 127;
  int k = o & 511;
  const float4 v = *(const float4*)(w + ((size_t)b * NNODE + node) * 512 + k);
  unsigned int p0 = (unsigned int)f2bf(v.x) | ((unsigned int)f2bf(v.y) << 16);
  unsigned int p1 = (unsigned int)f2bf(v.z) | ((unsigned int)f2bf(v.w) << 16);
  *(uint2*)(xbf + o) = make_uint2(p0, p1);
}

// ---------------------------------------------------------------------------
// Gate-interleaved transposed weights (c = column index, k = reduction index):
//  WL2t (768,512):  c = 48G+16g+mi, g in {i,u,o}
//  WA2t (1280,320): c = 80G+16g+mi, g in {i,f,g,o,fh}
//  WH2t (1024,256): c = 64G+16g+mi, g in {i,f,g,o}
//  WEX2t(1024,768): c = 64G+16g+mi, g in {i,u,o,f}; k<256 h-weights, k>=256 x-weights
__global__ void k_prep_w(const float* __restrict__ Wix, const float* __restrict__ Wux,
                         const float* __restrict__ Wox, const float* __restrict__ Wfx,
                         const float* __restrict__ Wih, const float* __restrict__ Wuh,
                         const float* __restrict__ Woh, const float* __restrict__ Wfh,
                         const float* __restrict__ Wsi, const float* __restrict__ Wsh,
                         unsigned short* __restrict__ WL2t, unsigned short* __restrict__ WA2t,
                         unsigned short* __restrict__ WH2t, unsigned short* __restrict__ WEX2t) {
  int idx = blockIdx.x * 256 + threadIdx.x;
  if (idx < 393216) {                       // WL2t 768*512
    int c = idx >> 9, k = idx & 511;
    int G = c / 48, rem = c - G * 48, g = rem >> 4, mi = rem & 15, m = G * 16 + mi;
    const float* W = (g == 0) ? Wix : (g == 1) ? Wux : Wox;
    WL2t[idx] = f2bf(W[k * 256 + m]);
  } else if (idx < 802816) {                // WA2t 1280*320
    int o = idx - 393216;
    int c = o / 320, k = o - c * 320;
    int G = c / 80, rem = c - G * 80, g = rem >> 4, mi = rem & 15, m = G * 16 + mi;
    float v;
    if (g < 4) v = Wsi[k * 1024 + g * 256 + m];
    else       v = (k < 256) ? Wfh[k * 256 + m] : 0.0f;
    WA2t[o] = f2bf(v);
  } else if (idx < 1064960) {               // WH2t 1024*256
    int o = idx - 802816;
    int c = o >> 8, k = o & 255;
    int G = c >> 6, rem = c & 63, g = rem >> 4, mi = rem & 15, m = G * 16 + mi;
    WH2t[o] = f2bf(Wsh[k * 1024 + g * 256 + m]);
  } else if (idx < 1851392) {               // WEX2t 1024*768
    int o = idx - 1064960;
    int c = o / 768, k = o - c * 768;
    int G = c >> 6, rem = c & 63, g = rem >> 4, mi = rem & 15, m = G * 16 + mi;
    float v;
    if (k < 256) {
      v = (g == 0) ? Wih[k * 256 + m] : (g == 1) ? Wuh[k * 256 + m]
        : (g == 2) ? Woh[k * 256 + m] : 0.0f;
    } else {
      int k2 = k - 256;
      v = (g == 0) ? Wix[k2 * 256 + m] : (g == 1) ? Wux[k2 * 256 + m]
        : (g == 2) ? Wox[k2 * 256 + m] : Wfx[k2 * 256 + m];
    }
    WEX2t[o] = f2bf(v);
  }
}

// Swizzled MFMA inner step reading buffers AP/BP. LDS row stride 64 shorts;
// k-slot XOR swizzle. sw(kk) = (kk | q*8) ^ ((m16&7)*8).
#define MFMA_BODY(AP, BP, NG, CW)                                             \
  _Pragma("unroll")                                                           \
  for (int kk = 0; kk < 64; kk += 32) {                                       \
    const int sw = (kk | (q * 8)) ^ ((m16 & 7) * 8);                          \
    s16x8 af[4], bfr[NG];                                                     \
    _Pragma("unroll")                                                         \
    for (int i = 0; i < 4; ++i)                                               \
      af[i] = *(const s16x8*)(&(AP)[(wm + i * 16 + m16) * 64 + sw]);          \
    _Pragma("unroll")                                                         \
    for (int j = 0; j < NG; ++j)                                              \
      bfr[j] = *(const s16x8*)(&(BP)[(wc * CW + j * 16 + m16) * 64 + sw]);    \
    _Pragma("unroll")                                                         \
    for (int i = 0; i < 4; ++i)                                               \
      _Pragma("unroll")                                                       \
      for (int j = 0; j < NG; ++j)                                            \
        acc[i][j] = __builtin_amdgcn_mfma_f32_16x16x32_bf16(af[i], bfr[j], acc[i][j], 0, 0, 0); \
  }

// Stage R rows x 64 shorts from SRC (row stride STRIDE shorts, k offset K0)
// into DST via global_load_lds. Wave w covers rows [w*R/4,(w+1)*R/4).
#define STAGE(DST, SRC, STRIDE, R, K0)                                        \
  _Pragma("unroll")                                                           \
  for (int c = 0; c < (R) / 32; ++c) {                                        \
    int row8 = wave * ((R) / 4) + c * 8;                                      \
    load16_lds(SRC + (size_t)(row8 + l8) * (STRIDE) + (K0) + gsw, &(DST)[row8 * 64]); \
  }

// K-step sync: drain all but the VM newest VMEM ops (buf[t]'s loads were
// issued a full step ago; the just-issued prefetch stays in flight), barrier,
// pin schedule. Post-MFMA raw barrier guards WAR on buffer reuse.
#define STEP_SYNC(VM)                                                         \
  s_wait_vmcnt<VM>();                                                         \
  __builtin_amdgcn_s_barrier();                                               \
  __builtin_amdgcn_sched_barrier(0);

// ---------------------------------------------------------------------------
// GEMM1 + cell1 epilogue. A = [AinL ; AinR] (2*crows x 320 bf16), B = WA2t.
// L rows -> h1 (bf16), c1, FHL.  R rows -> PR (float4 i,f,g,o preacts), FHR.
__global__ __launch_bounds__(256, 2) void k_gemm1(
    const unsigned short* __restrict__ AinL, const unsigned short* __restrict__ AinR,
    const unsigned short* __restrict__ Bt,
    unsigned short* __restrict__ h1, float* __restrict__ c1,
    float* __restrict__ FHL, float* __restrict__ FHR, float* __restrict__ PR,
    const float* __restrict__ bsi, const float* __restrict__ bsh, int crows) {
  __shared__ alignas(16) unsigned short As[2][128 * 64];
  __shared__ alignas(16) unsigned short Bs[2][160 * 64];
  int bx, by; swz_blk(bx, by);
  const int t = threadIdx.x;
  const int wave = t >> 6, lane = t & 63;
  const int wm = (wave & 1) * 64, wc = wave >> 1;
  const int m16 = lane & 15, q = lane >> 4;
  const int l8 = lane >> 3, l7 = lane & 7;
  const int gsw = ((l7 ^ l8) * 8);
  const int rowBase = by * 128;
  const bool isL = rowBase < crows;
  const unsigned short* Arow = isL ? (AinL + (size_t)rowBase * 320)
                                   : (AinR + (size_t)(rowBase - crows) * 320);
  const unsigned short* Brow = Bt + (size_t)bx * 160 * 320;
  f32x4 acc[4][5] = {};
  const int m = (bx * 2 + wc) * 16 + m16;

  // Bias hoist: issued before the K-loop; counted waits drain them first.
  float bi = 0.f, bg = 0.f, bo = 0.f;
  if (isL) {
    bi = bsi[m] + bsh[m];
    bg = bsi[512 + m] + bsh[512 + m];
    bo = bsi[768 + m] + bsh[768 + m];
  }

  STAGE(As[0], Arow, 320, 128, 0)
  STAGE(Bs[0], Brow, 320, 160, 0)
#pragma unroll
  for (int ti = 0; ti < 5; ++ti) {
    if (ti < 4) {
      STAGE(As[(ti + 1) & 1], Arow, 320, 128, (ti + 1) * 64)
      STAGE(Bs[(ti + 1) & 1], Brow, 320, 160, (ti + 1) * 64)
      STEP_SYNC(9)
    } else {
      STEP_SYNC(0)
    }
    MFMA_BODY(As[ti & 1], Bs[ti & 1], 5, 80)
    __builtin_amdgcn_s_barrier();
  }

  if (isL) {
#pragma unroll
    for (int i = 0; i < 4; ++i)
#pragma unroll
      for (int r2 = 0; r2 < 4; ++r2) {
        int r = rowBase + wm + i * 16 + q * 4 + r2;
        float ii = sigf(acc[i][0][r2] + bi);
        float gg = tanh_a(acc[i][2][r2] + bg);
        float oo = sigf(acc[i][3][r2] + bo);
        float cv = ii * gg;
        size_t o = (size_t)r * 256 + m;
        h1[o] = f2bf(oo * tanh_a(cv));
        c1[o] = cv;
        FHL[o] = acc[i][4][r2];
      }
  } else {
#pragma unroll
    for (int i = 0; i < 4; ++i)
#pragma unroll
      for (int r2 = 0; r2 < 4; ++r2) {
        int rr = rowBase - crows + wm + i * 16 + q * 4 + r2;
        size_t o = (size_t)rr * 256 + m;
        float4 pv = {acc[i][0][r2], acc[i][1][r2], acc[i][2][r2], acc[i][3][r2]};
        *(float4*)(PR + o * 4) = pv;
        FHR[o] = acc[i][4][r2];
      }
  }
}

// ---------------------------------------------------------------------------
// GEMM2 + cell2 epilogue. A = h1 (crows x 256), B = WH2t.
// g = acc + PR + b_seq; h_tilde -> HT (bf16). PR/c1 prefetched under the
// last two MFMA bodies (T14).
__global__ __launch_bounds__(256, 2) void k_gemm2(
    const unsigned short* __restrict__ A, const unsigned short* __restrict__ Bt,
    const float* __restrict__ PR, const float* __restrict__ c1,
    unsigned short* __restrict__ HT,
    const float* __restrict__ bsi, const float* __restrict__ bsh) {
  __shared__ alignas(16) unsigned short As[2][128 * 64];
  __shared__ alignas(16) unsigned short Bs[2][128 * 64];
  int bx, by; swz_blk(bx, by);
  const int t = threadIdx.x;
  const int wave = t >> 6, lane = t & 63;
  const int wm = (wave & 1) * 64, wc = wave >> 1;
  const int m16 = lane & 15, q = lane >> 4;
  const int l8 = lane >> 3, l7 = lane & 7;
  const int gsw = ((l7 ^ l8) * 8);
  const int rowBase = by * 128;
  const unsigned short* Arow = A + (size_t)rowBase * 256;
  const unsigned short* Brow = Bt + (size_t)bx * 128 * 256;
  f32x4 acc[4][4] = {};
  const int m = (bx * 2 + wc) * 16 + m16;

  float b0 = bsi[m] + bsh[m];
  float b1 = bsi[256 + m] + bsh[256 + m];
  float b2 = bsi[512 + m] + bsh[512 + m];
  float b3 = bsi[768 + m] + bsh[768 + m];

  float4 ppr[4][4];
  float pc[4][4];

  STAGE(As[0], Arow, 256, 128, 0)
  STAGE(Bs[0], Brow, 256, 128, 0)
#pragma unroll
  for (int ti = 0; ti < 4; ++ti) {
    if (ti < 3) {
      STAGE(As[(ti + 1) & 1], Arow, 256, 128, (ti + 1) * 64)
      STAGE(Bs[(ti + 1) & 1], Brow, 256, 128, (ti + 1) * 64)
      STEP_SYNC(8)
      if (ti == 2) {
        // Epilogue prefetch: 16 float4 + 16 float loads (32 instrs), newest.
#pragma unroll
        for (int i = 0; i < 4; ++i)
#pragma unroll
          for (int r2 = 0; r2 < 4; ++r2) {
            int r = rowBase + wm + i * 16 + q * 4 + r2;
            size_t o = (size_t)r * 256 + m;
            ppr[i][r2] = *(const float4*)(PR + o * 4);
            pc[i][r2] = c1[o];
          }
      }
    } else {
      STEP_SYNC(32)   // drain stage(3) (8 oldest); prefetch stays in flight
    }
    MFMA_BODY(As[ti & 1], Bs[ti & 1], 4, 64)
    __builtin_amdgcn_s_barrier();
  }

#pragma unroll
  for (int i = 0; i < 4; ++i)
#pragma unroll
    for (int r2 = 0; r2 < 4; ++r2) {
      int r = rowBase + wm + i * 16 + q * 4 + r2;
      size_t o = (size_t)r * 256 + m;
      float4 pv = ppr[i][r2];
      float ii = sigf(acc[i][0][r2] + pv.x + b0);
      float ff = sigf(acc[i][1][r2] + pv.y + b1);
      float gg = tanh_a(acc[i][2][r2] + pv.z + b2);
      float oo = sigf(acc[i][3][r2] + pv.w + b3);
      float c2 = ff * pc[i][r2] + ii * gg;
      HT[o] = f2bf(oo * tanh_a(c2));
    }
}

// ---------------------------------------------------------------------------
// GEMM3 + node-gate epilogue. A = [HT | xbf-slice] (crows x 768 bf16),
// B = WEX2t (gates i,u,o,f). FHL/FHR + children cbuf prefetched under the
// last two MFMA bodies (T14; 64 loads -- the round-7 profile's hidden cost).
// lvl>0: write cbuf + parent Ain (h bf16, rel). lvl==0: write d_out fp32.
__global__ __launch_bounds__(256, 2) void k_gemm3(
    const unsigned short* __restrict__ HT, const unsigned short* __restrict__ xnode,
    const unsigned short* __restrict__ Bt,
    const float* __restrict__ FHL, const float* __restrict__ FHR,
    float* __restrict__ cbuf, unsigned short* __restrict__ Ain,
    const float* __restrict__ rel, float* __restrict__ out,
    const float* __restrict__ bix, const float* __restrict__ bih,
    const float* __restrict__ bux, const float* __restrict__ buh,
    const float* __restrict__ box, const float* __restrict__ boh,
    const float* __restrict__ bfx, const float* __restrict__ bfh,
    int base, int v0, int n, int lvl) {
  __shared__ alignas(16) unsigned short As[2][128 * 64];
  __shared__ alignas(16) unsigned short Bs[2][128 * 64];
  int bx, by; swz_blk(bx, by);
  const int t = threadIdx.x;
  const int wave = t >> 6, lane = t & 63;
  const int wm = (wave & 1) * 64, wc = wave >> 1;
  const int m16 = lane & 15, q = lane >> 4;
  const int l8 = lane >> 3, l7 = lane & 7;
  const int gsw = ((l7 ^ l8) * 8);
  const int rowBase = by * 128;
  const unsigned short* Brow = Bt + (size_t)bx * 128 * 768;
  f32x4 acc[4][4] = {};
  const int m = (bx * 2 + wc) * 16 + m16;

  float bi = bix[m] + bih[m];
  float bu = bux[m] + buh[m];
  float bo = box[m] + boh[m];
  float bf = bfx[m] + bfh[m];

  float pfl[4][4], pfr[4][4], pc0[4][4], pc1v[4][4];

  // A source: k<256 from HT (stride 256), k>=256 from xnode (stride 512).
  auto stageA = [&](unsigned short* dst, int kb) {
    if (kb < 256) {
      const unsigned short* Arow = HT + (size_t)rowBase * 256;
#pragma unroll
      for (int c = 0; c < 4; ++c) {
        int row8 = wave * 32 + c * 8;
        load16_lds(Arow + (size_t)(row8 + l8) * 256 + kb + gsw, &dst[row8 * 64]);
      }
    } else {
      const unsigned short* Arow = xnode + (size_t)rowBase * 512;
      int k0 = kb - 256;
#pragma unroll
      for (int c = 0; c < 4; ++c) {
        int row8 = wave * 32 + c * 8;
        load16_lds(Arow + (size_t)(row8 + l8) * 512 + k0 + gsw, &dst[row8 * 64]);
      }
    }
  };

  stageA(As[0], 0);
  STAGE(Bs[0], Brow, 768, 128, 0)
#pragma unroll
  for (int ti = 0; ti < 12; ++ti) {
    if (ti < 11) {
      stageA(As[(ti + 1) & 1], (ti + 1) * 64);
      STAGE(Bs[(ti + 1) & 1], Brow, 768, 128, (ti + 1) * 64)
      STEP_SYNC(8)
      if (ti == 10) {
        // Epilogue prefetch: 64 scalar loads (FHL/FHR/cbuf children).
#pragma unroll
        for (int i = 0; i < 4; ++i)
#pragma unroll
          for (int r2 = 0; r2 < 4; ++r2) {
            int r = rowBase + wm + i * 16 + q * 4 + r2;
            int b = r & 127;
            int node = base + v0 + (r >> 7);
            size_t o = (size_t)r * 256 + m;
            size_t co = ((size_t)(2 * node + 1) * 128 + b) * 256 + m;
            pfl[i][r2] = FHL[o];
            pfr[i][r2] = FHR[o];
            pc0[i][r2] = cbuf[co];
            pc1v[i][r2] = cbuf[co + 32768];
          }
      }
    } else {
      STEP_SYNC(63)   // outstanding = 8 stage + 64 prefetch; drain 9 oldest
    }
    MFMA_BODY(As[ti & 1], Bs[ti & 1], 4, 64)
    __builtin_amdgcn_s_barrier();
  }

#pragma unroll
  for (int i = 0; i < 4; ++i)
#pragma unroll
    for (int r2 = 0; r2 < 4; ++r2) {
      int r = rowBase + wm + i * 16 + q * 4 + r2;
      int vloc = r >> 7, b = r & 127;
      int vg = v0 + vloc;
      int node = base + vg;
      size_t o = (size_t)r * 256 + m;
      float pf = acc[i][3][r2] + bf;
      float f0 = sigf(pf + pfl[i][r2]);
      float f1 = sigf(pf + pfr[i][r2]);
      float ii = sigf(acc[i][0][r2] + bi);
      float uu = tanh_a(acc[i][1][r2] + bu);
      float oo = sigf(acc[i][2][r2] + bo);
      float cc = ii * uu + f0 * pc0[i][r2] + f1 * pc1v[i][r2];
      float hh = oo * tanh_a(cc);
      if (lvl == 0) {
        out[b * 256 + m] = hh;
      } else {
        cbuf[((size_t)node * 128 + b) * 256 + m] = cc;
        int rowA = (vg & 1) * (n >> 1) * 128 + (vg >> 1) * 128 + b;
        Ain[(size_t)rowA * 320 + m] = f2bf(hh);
        if (m < 64)
          Ain[(size_t)rowA * 320 + 256 + m] = f2bf(rel[((size_t)b * NNODE + node) * 64 + m]);
      }
    }
}

// ---------------------------------------------------------------------------
// Leaf GEMM + epilogue. A = xbf leaf slice (32768 x 512 bf16), B = WL2t
// (gates i,u,o). c = i*u; writes cbuf + level-7 Ain.
__global__ __launch_bounds__(256, 2) void k_leaf(
    const unsigned short* __restrict__ xleaf, const unsigned short* __restrict__ Bt,
    float* __restrict__ cbuf, unsigned short* __restrict__ Ain,
    const float* __restrict__ rel,
    const float* __restrict__ bix, const float* __restrict__ bih,
    const float* __restrict__ bux, const float* __restrict__ buh,
    const float* __restrict__ box, const float* __restrict__ boh) {
  __shared__ alignas(16) unsigned short As[2][128 * 64];
  __shared__ alignas(16) unsigned short Bs[2][96 * 64];
  int bx, by; swz_blk(bx, by);
  const int t = threadIdx.x;
  const int wave = t >> 6, lane = t & 63;
  const int wm = (wave & 1) * 64, wc = wave >> 1;
  const int m16 = lane & 15, q = lane >> 4;
  const int l8 = lane >> 3, l7 = lane & 7;
  const int gsw = ((l7 ^ l8) * 8);
  const int rowBase = by * 128;
  const unsigned short* Arow = xleaf + (size_t)rowBase * 512;
  const unsigned short* Brow = Bt + (size_t)bx * 96 * 512;
  f32x4 acc[4][3] = {};
  const int m = (bx * 2 + wc) * 16 + m16;

  float bi = bix[m] + bih[m];
  float bu = bux[m] + buh[m];
  float bo = box[m] + boh[m];

  STAGE(As[0], Arow, 512, 128, 0)
#pragma unroll
  for (int c = 0; c < 3; ++c) {
    int row8 = wave * 24 + c * 8;
    load16_lds(Brow + (size_t)(row8 + l8) * 512 + 0 + gsw, &Bs[0][row8 * 64]);
  }
#pragma unroll
  for (int ti = 0; ti < 8; ++ti) {
    if (ti < 7) {
      int kn = (ti + 1) * 64;
      STAGE(As[(ti + 1) & 1], Arow, 512, 128, kn)
#pragma unroll
      for (int c = 0; c < 3; ++c) {
        int row8 = wave * 24 + c * 8;
        load16_lds(Brow + (size_t)(row8 + l8) * 512 + kn + gsw, &Bs[(ti + 1) & 1][row8 * 64]);
      }
      STEP_SYNC(7)
    } else {
      STEP_SYNC(0)
    }
    MFMA_BODY(As[ti & 1], Bs[ti & 1], 3, 48)
    __builtin_amdgcn_s_barrier();
  }

#pragma unroll
  for (int i = 0; i < 4; ++i)
#pragma unroll
    for (int r2 = 0; r2 < 4; ++r2) {
      int r = rowBase + wm + i * 16 + q * 4 + r2;
      int vg = r >> 7, b = r & 127;
      int node = 255 + vg;
      float ii = sigf(acc[i][0][r2] + bi);
      float uu = tanh_a(acc[i][1][r2] + bu);
      float oo = sigf(acc[i][2][r2] + bo);
      float cc = ii * uu;
      float hh = oo * tanh_a(cc);
      cbuf[((size_t)node * 128 + b) * 256 + m] = cc;
      int rowA = (vg & 1) * 16384 + (vg >> 1) * 128 + b;
      Ain[(size_t)rowA * 320 + m] = f2bf(hh);
      if (m < 64)
        Ain[(size_t)rowA * 320 + 256 + m] = f2bf(rel[((size_t)b * NNODE + node) * 64 + m]);
    }
}

// ---------------------------------------------------------------------------
extern "C" void kernel_launch(void* const* d_in, const int* in_sizes, int n_in,
                              void* d_out, int out_size, void* d_ws, size_t ws_size,
                              hipStream_t stream) {
  const float* wte = (const float*)d_in[0];
  const float* rel = (const float*)d_in[1];
  const float* Wix = (const float*)d_in[3];
  const float* bix = (const float*)d_in[4];
  const float* Wfx = (const float*)d_in[5];
  const float* bfx = (const float*)d_in[6];
  const float* Wux = (const float*)d_in[7];
  const float* bux = (const float*)d_in[8];
  const float* Wox = (const float*)d_in[9];
  const float* box = (const float*)d_in[10];
  const float* Wih = (const float*)d_in[11];
  const float* bih = (const float*)d_in[12];
  const float* Wfh = (const float*)d_in[13];
  const float* bfh = (const float*)d_in[14];
  const float* Wuh = (const float*)d_in[15];
  const float* buh = (const float*)d_in[16];
  const float* Woh = (const float*)d_in[17];
  const float* boh = (const float*)d_in[18];
  const float* Wsi = (const float*)d_in[19];
  const float* Wsh = (const float*)d_in[20];
  const float* bsi = (const float*)d_in[21];
  const float* bsh = (const float*)d_in[22];
  float* out = (float*)d_out;
  (void)in_sizes; (void)n_in; (void)out_size;

  int INT_MAXN;
  if (ws_size >= (size_t)310 * 1024 * 1024)      INT_MAXN = 128;
  else if (ws_size >= (size_t)200 * 1024 * 1024) INT_MAXN = 32;
  else                                           INT_MAXN = 8;
  const int crowsMax = INT_MAXN * 128;

  char* ws = (char*)d_ws;
  size_t off = 0;
  auto alloc = [&](size_t bytes) {
    size_t o = off; off += (bytes + 255) & ~(size_t)255; return o;
  };
  unsigned short* xbf  = (unsigned short*)(ws + alloc((size_t)NNODE * 128 * 512 * 2));
  float*          cbuf = (float*)         (ws + alloc((size_t)NNODE * 128 * 256 * 4));
  unsigned short* Ain  = (unsigned short*)(ws + alloc((size_t)32768 * 320 * 2));
  unsigned short* WL2t = (unsigned short*)(ws + alloc((size_t)768 * 512 * 2));
  unsigned short* WA2t = (unsigned short*)(ws + alloc((size_t)1280 * 320 * 2));
  unsigned short* WH2t = (unsigned short*)(ws + alloc((size_t)1024 * 256 * 2));
  unsigned short* WEX2t= (unsigned short*)(ws + alloc((size_t)1024 * 768 * 2));
  unsigned short* h1   = (unsigned short*)(ws + alloc((size_t)crowsMax * 256 * 2));
  float*          c1   = (float*)         (ws + alloc((size_t)crowsMax * 256 * 4));
  float*          FHL  = (float*)         (ws + alloc((size_t)crowsMax * 256 * 4));
  float*          FHR  = (float*)         (ws + alloc((size_t)crowsMax * 256 * 4));
  float*          PR   = (float*)         (ws + alloc((size_t)crowsMax * 1024 * 4));
  unsigned short* HT   = (unsigned short*)(ws + alloc((size_t)crowsMax * 256 * 2));

  k_prep_x<<<32704, 256, 0, stream>>>(wte, xbf);
  k_prep_w<<<7232, 256, 0, stream>>>(Wix, Wux, Wox, Wfx, Wih, Wuh, Woh, Wfh,
                                     Wsi, Wsh, WL2t, WA2t, WH2t, WEX2t);

  // Leaves: one fused GEMM over xbf rows [255*128, 511*128).
  k_leaf<<<dim3(8, 256), 256, 0, stream>>>(xbf + (size_t)255 * 128 * 512, WL2t,
                                           cbuf, Ain, rel, bix, bih, bux, buh, box, boh);

  // Internal levels 7..0, 3 fused launches per chunk.
  for (int lvl = 7; lvl >= 0; --lvl) {
    int n = 1 << lvl;
    int base = n - 1;
    int cn = (n < INT_MAXN) ? n : INT_MAXN;
    for (int v0 = 0; v0 < n; v0 += cn) {
      int crows = cn * 128;
      const unsigned short* AinL = Ain + (size_t)(v0 * 128) * 320;
      const unsigned short* AinR = Ain + (size_t)((n + v0) * 128) * 320;
      const unsigned short* xnode = xbf + (size_t)(base + v0) * 128 * 512;
      k_gemm1<<<dim3(8, 2 * cn), 256, 0, stream>>>(AinL, AinR, WA2t, h1, c1,
                                                   FHL, FHR, PR, bsi, bsh, crows);
      k_gemm2<<<dim3(8, cn), 256, 0, stream>>>(h1, WH2t, PR, c1, HT, bsi, bsh);
      k_gemm3<<<dim3(8, cn), 256, 0, stream>>>(HT, xnode, WEX2t, FHL, FHR, cbuf, Ain,
                                               rel, out, bix, bih, bux, buh, box, boh,
                                               bfx, bfh, base, v0, n, lvl);
    }
  }
}

// Round 5
// 742.453 us; speedup vs baseline: 1.3847x; 1.0034x over previous
//
#include <hip/hip_runtime.h>
#include <math.h>

// N=511 complete binary tree: nodes 0..254 internal, 255..510 leaves.
// B=128, M=256, IN=512, R=64.
// Gate-interleaved bf16 weight layouts fuse every LSTM-cell epilogue into its
// producing GEMM. GEMM staging uses global_load_lds width=16; LDS tiles are
// unpadded (stride 64 shorts) with an XOR k-slot swizzle compensated in the
// per-lane global source address (ds_read_b128 conflict-free).
// Round 5: fast exp2/rcp transcendentals + XCD block remap (VALU 33->14%).
// Round 6/7: dbuf + counted-vmcnt K-loop (T3/T4) -- null on gemm3, helped
// gemm1/2/leaf (-95 us total). Round 8: VGPR cap 256 + epilogue operand
// prefetch (-40 us).
// Round 9: eliminate PR (134 MB write + 134 MB read per iter). Algebra:
// g2 = h1@Wsh + AinR@Wsi + b, so gemm2 takes A2=[h1|AinR] (K=576) against
// B2=[Wsh;Wsi] with a 5th fh column group (Wfh on the AinR-h K-range) that
// yields FHR. gemm1 halves (L rows only); PR tensor + its stores/loads gone.
#define NNODE 511

typedef short s16x8 __attribute__((ext_vector_type(8)));
typedef float f32x4 __attribute__((ext_vector_type(4)));

__device__ __forceinline__ unsigned short f2bf(float f) {
  unsigned int u = __builtin_bit_cast(unsigned int, f);
  u += 0x7fffu + ((u >> 16) & 1u);           // RNE
  return (unsigned short)(u >> 16);
}
// Fast sigmoid/tanh via v_exp_f32 (2^x) + v_rcp_f32. ~1 ulp vs libm.
__device__ __forceinline__ float sigf(float x) {
  float e = __builtin_amdgcn_exp2f(-1.442695040888963f * x);
  return __builtin_amdgcn_rcpf(1.0f + e);
}
__device__ __forceinline__ float tanh_a(float x) {
  float e = __builtin_amdgcn_exp2f(2.885390081777927f * x);
  return 1.0f - 2.0f * __builtin_amdgcn_rcpf(1.0f + e);
}

__device__ __forceinline__ void load16_lds(const unsigned short* g, unsigned short* l) {
  __builtin_amdgcn_global_load_lds(
      (const __attribute__((address_space(1))) void*)g,
      (__attribute__((address_space(3))) void*)l, 16, 0, 0);
}

template<int N> __device__ __forceinline__ void s_wait_vmcnt() {
  asm volatile("s_waitcnt vmcnt(%0)" :: "n"(N) : "memory");
}

// XCD-aware block remap (bijective when ny%8==0; tail launches L2-fit).
__device__ __forceinline__ void swz_blk(int& bx, int& by) {
  bx = blockIdx.x; by = blockIdx.y;
  int ny = gridDim.y;
  if ((ny & 7) == 0) {
    int lin = by * 8 + bx;
    int w = lin >> 3;
    by = (lin & 7) * (ny >> 3) + (w >> 3);
    bx = w & 7;
  }
}

// ---------------------------------------------------------------------------
// wte (B,511,512) fp32 -> xbf (node,b,k) bf16, node-major. One-time.
__global__ void k_prep_x(const float* __restrict__ w, unsigned short* __restrict__ xbf) {
  int o = (blockIdx.x * 256 + threadIdx.x) * 4;
  int node = o >> 16;
  int b = (o >> 9) & 127;
  int k = o & 511;
  const float4 v = *(const float4*)(w + ((size_t)b * NNODE + node) * 512 + k);
  unsigned int p0 = (unsigned int)f2bf(v.x) | ((unsigned int)f2bf(v.y) << 16);
  unsigned int p1 = (unsigned int)f2bf(v.z) | ((unsigned int)f2bf(v.w) << 16);
  *(uint2*)(xbf + o) = make_uint2(p0, p1);
}

// ---------------------------------------------------------------------------
// Gate-interleaved transposed weights (c = column index, k = reduction index):
//  WL2t (768,512):  c = 48G+16g+mi, g in {i,u,o}
//  WA2t (1280,320): c = 80G+16g+mi, g in {i,f,g,o,fh}
//  WG2t (1280,576): c = 80G+16g+mi, g in {i,f,g,o,fh};
//                   g<4: k<256 -> Wsh[k], k>=256 -> Wsi[k-256]
//                   g==4 (fh): 256<=k<512 -> Wfh[k-256], else 0
//  WEX2t(1024,768): c = 64G+16g+mi, g in {i,u,o,f}; k<256 h-w, k>=256 x-w
__global__ void k_prep_w(const float* __restrict__ Wix, const float* __restrict__ Wux,
                         const float* __restrict__ Wox, const float* __restrict__ Wfx,
                         const float* __restrict__ Wih, const float* __restrict__ Wuh,
                         const float* __restrict__ Woh, const float* __restrict__ Wfh,
                         const float* __restrict__ Wsi, const float* __restrict__ Wsh,
                         unsigned short* __restrict__ WL2t, unsigned short* __restrict__ WA2t,
                         unsigned short* __restrict__ WG2t, unsigned short* __restrict__ WEX2t) {
  int idx = blockIdx.x * 256 + threadIdx.x;
  if (idx < 393216) {                       // WL2t 768*512
    int c = idx >> 9, k = idx & 511;
    int G = c / 48, rem = c - G * 48, g = rem >> 4, mi = rem & 15, m = G * 16 + mi;
    const float* W = (g == 0) ? Wix : (g == 1) ? Wux : Wox;
    WL2t[idx] = f2bf(W[k * 256 + m]);
  } else if (idx < 802816) {                // WA2t 1280*320
    int o = idx - 393216;
    int c = o / 320, k = o - c * 320;
    int G = c / 80, rem = c - G * 80, g = rem >> 4, mi = rem & 15, m = G * 16 + mi;
    float v;
    if (g < 4) v = Wsi[k * 1024 + g * 256 + m];
    else       v = (k < 256) ? Wfh[k * 256 + m] : 0.0f;
    WA2t[o] = f2bf(v);
  } else if (idx < 1540096) {               // WG2t 1280*576
    int o = idx - 802816;
    int c = o / 576, k = o - c * 576;
    int G = c / 80, rem = c - G * 80, g = rem >> 4, mi = rem & 15, m = G * 16 + mi;
    float v;
    if (g < 4) v = (k < 256) ? Wsh[k * 1024 + g * 256 + m]
                             : Wsi[(k - 256) * 1024 + g * 256 + m];
    else       v = (k >= 256 && k < 512) ? Wfh[(k - 256) * 256 + m] : 0.0f;
    WG2t[o] = f2bf(v);
  } else if (idx < 2326528) {               // WEX2t 1024*768
    int o = idx - 1540096;
    int c = o / 768, k = o - c * 768;
    int G = c >> 6, rem = c & 63, g = rem >> 4, mi = rem & 15, m = G * 16 + mi;
    float v;
    if (k < 256) {
      v = (g == 0) ? Wih[k * 256 + m] : (g == 1) ? Wuh[k * 256 + m]
        : (g == 2) ? Woh[k * 256 + m] : 0.0f;
    } else {
      int k2 = k - 256;
      v = (g == 0) ? Wix[k2 * 256 + m] : (g == 1) ? Wux[k2 * 256 + m]
        : (g == 2) ? Wox[k2 * 256 + m] : Wfx[k2 * 256 + m];
    }
    WEX2t[o] = f2bf(v);
  }
}

// Swizzled MFMA inner step reading buffers AP/BP. LDS row stride 64 shorts;
// k-slot XOR swizzle. sw(kk) = (kk | q*8) ^ ((m16&7)*8).
#define MFMA_BODY(AP, BP, NG, CW)                                             \
  _Pragma("unroll")                                                           \
  for (int kk = 0; kk < 64; kk += 32) {                                       \
    const int sw = (kk | (q * 8)) ^ ((m16 & 7) * 8);                          \
    s16x8 af[4], bfr[NG];                                                     \
    _Pragma("unroll")                                                         \
    for (int i = 0; i < 4; ++i)                                               \
      af[i] = *(const s16x8*)(&(AP)[(wm + i * 16 + m16) * 64 + sw]);          \
    _Pragma("unroll")                                                         \
    for (int j = 0; j < NG; ++j)                                              \
      bfr[j] = *(const s16x8*)(&(BP)[(wc * CW + j * 16 + m16) * 64 + sw]);    \
    _Pragma("unroll")                                                         \
    for (int i = 0; i < 4; ++i)                                               \
      _Pragma("unroll")                                                       \
      for (int j = 0; j < NG; ++j)                                            \
        acc[i][j] = __builtin_amdgcn_mfma_f32_16x16x32_bf16(af[i], bfr[j], acc[i][j], 0, 0, 0); \
  }

#define STAGE(DST, SRC, STRIDE, R, K0)                                        \
  _Pragma("unroll")                                                           \
  for (int c = 0; c < (R) / 32; ++c) {                                        \
    int row8 = wave * ((R) / 4) + c * 8;                                      \
    load16_lds(SRC + (size_t)(row8 + l8) * (STRIDE) + (K0) + gsw, &(DST)[row8 * 64]); \
  }

// K-step sync: drain all but the VM newest VMEM ops, barrier, pin schedule.
#define STEP_SYNC(VM)                                                         \
  s_wait_vmcnt<VM>();                                                         \
  __builtin_amdgcn_s_barrier();                                               \
  __builtin_amdgcn_sched_barrier(0);

// ---------------------------------------------------------------------------
// GEMM1 + cell1 epilogue. A = AinL (crows x 320 bf16), B = WA2t.
// -> h1 (bf16), c1, FHL.
__global__ __launch_bounds__(256, 2) void k_gemm1(
    const unsigned short* __restrict__ AinL, const unsigned short* __restrict__ Bt,
    unsigned short* __restrict__ h1, float* __restrict__ c1,
    float* __restrict__ FHL,
    const float* __restrict__ bsi, const float* __restrict__ bsh) {
  __shared__ alignas(16) unsigned short As[2][128 * 64];
  __shared__ alignas(16) unsigned short Bs[2][160 * 64];
  int bx, by; swz_blk(bx, by);
  const int t = threadIdx.x;
  const int wave = t >> 6, lane = t & 63;
  const int wm = (wave & 1) * 64, wc = wave >> 1;
  const int m16 = lane & 15, q = lane >> 4;
  const int l8 = lane >> 3, l7 = lane & 7;
  const int gsw = ((l7 ^ l8) * 8);
  const int rowBase = by * 128;
  const unsigned short* Arow = AinL + (size_t)rowBase * 320;
  const unsigned short* Brow = Bt + (size_t)bx * 160 * 320;
  f32x4 acc[4][5] = {};
  const int m = (bx * 2 + wc) * 16 + m16;

  float bi = bsi[m] + bsh[m];
  float bg = bsi[512 + m] + bsh[512 + m];
  float bo = bsi[768 + m] + bsh[768 + m];

  STAGE(As[0], Arow, 320, 128, 0)
  STAGE(Bs[0], Brow, 320, 160, 0)
#pragma unroll
  for (int ti = 0; ti < 5; ++ti) {
    if (ti < 4) {
      STAGE(As[(ti + 1) & 1], Arow, 320, 128, (ti + 1) * 64)
      STAGE(Bs[(ti + 1) & 1], Brow, 320, 160, (ti + 1) * 64)
      STEP_SYNC(9)
    } else {
      STEP_SYNC(0)
    }
    MFMA_BODY(As[ti & 1], Bs[ti & 1], 5, 80)
    __builtin_amdgcn_s_barrier();
  }

#pragma unroll
  for (int i = 0; i < 4; ++i)
#pragma unroll
    for (int r2 = 0; r2 < 4; ++r2) {
      int r = rowBase + wm + i * 16 + q * 4 + r2;
      float ii = sigf(acc[i][0][r2] + bi);
      float gg = tanh_a(acc[i][2][r2] + bg);
      float oo = sigf(acc[i][3][r2] + bo);
      float cv = ii * gg;
      size_t o = (size_t)r * 256 + m;
      h1[o] = f2bf(oo * tanh_a(cv));
      c1[o] = cv;
      FHL[o] = acc[i][4][r2];
    }
}

// ---------------------------------------------------------------------------
// GEMM2 + cell2 epilogue. A = [h1 | AinR] (crows x 576 bf16), B = WG2t
// (gates i,f,g,o,fh). c2 = sig(f)*c1 + sig(i)*tanh(g); HT = sig(o)*tanh(c2);
// FHR = fh preact. c1 prefetched under the last MFMA body (T14).
__global__ __launch_bounds__(256, 2) void k_gemm2(
    const unsigned short* __restrict__ h1, const unsigned short* __restrict__ AinR,
    const unsigned short* __restrict__ Bt,
    const float* __restrict__ c1, unsigned short* __restrict__ HT,
    float* __restrict__ FHR,
    const float* __restrict__ bsi, const float* __restrict__ bsh) {
  __shared__ alignas(16) unsigned short As[2][128 * 64];
  __shared__ alignas(16) unsigned short Bs[2][160 * 64];
  int bx, by; swz_blk(bx, by);
  const int t = threadIdx.x;
  const int wave = t >> 6, lane = t & 63;
  const int wm = (wave & 1) * 64, wc = wave >> 1;
  const int m16 = lane & 15, q = lane >> 4;
  const int l8 = lane >> 3, l7 = lane & 7;
  const int gsw = ((l7 ^ l8) * 8);
  const int rowBase = by * 128;
  const unsigned short* Brow = Bt + (size_t)bx * 160 * 576;
  f32x4 acc[4][5] = {};
  const int m = (bx * 2 + wc) * 16 + m16;

  float b0 = bsi[m] + bsh[m];
  float b1 = bsi[256 + m] + bsh[256 + m];
  float b2 = bsi[512 + m] + bsh[512 + m];
  float b3 = bsi[768 + m] + bsh[768 + m];

  float pc[4][4];

  // A source: k<256 from h1 (stride 256), k>=256 from AinR (stride 320).
  auto stageA = [&](unsigned short* dst, int kb) {
    if (kb < 256) {
      const unsigned short* Arow = h1 + (size_t)rowBase * 256;
#pragma unroll
      for (int c = 0; c < 4; ++c) {
        int row8 = wave * 32 + c * 8;
        load16_lds(Arow + (size_t)(row8 + l8) * 256 + kb + gsw, &dst[row8 * 64]);
      }
    } else {
      const unsigned short* Arow = AinR + (size_t)rowBase * 320;
      int k0 = kb - 256;
#pragma unroll
      for (int c = 0; c < 4; ++c) {
        int row8 = wave * 32 + c * 8;
        load16_lds(Arow + (size_t)(row8 + l8) * 320 + k0 + gsw, &dst[row8 * 64]);
      }
    }
  };

  stageA(As[0], 0);
  STAGE(Bs[0], Brow, 576, 160, 0)
#pragma unroll
  for (int ti = 0; ti < 9; ++ti) {
    if (ti < 8) {
      stageA(As[(ti + 1) & 1], (ti + 1) * 64);
      STAGE(Bs[(ti + 1) & 1], Brow, 576, 160, (ti + 1) * 64)
      STEP_SYNC(9)
      if (ti == 7) {
        // Epilogue prefetch: 16 c1 loads, newest in the queue.
#pragma unroll
        for (int i = 0; i < 4; ++i)
#pragma unroll
          for (int r2 = 0; r2 < 4; ++r2) {
            int r = rowBase + wm + i * 16 + q * 4 + r2;
            pc[i][r2] = c1[(size_t)r * 256 + m];
          }
      }
    } else {
      STEP_SYNC(16)   // drain the 9 stage loads; c1 prefetch stays in flight
    }
    MFMA_BODY(As[ti & 1], Bs[ti & 1], 5, 80)
    __builtin_amdgcn_s_barrier();
  }

#pragma unroll
  for (int i = 0; i < 4; ++i)
#pragma unroll
    for (int r2 = 0; r2 < 4; ++r2) {
      int r = rowBase + wm + i * 16 + q * 4 + r2;
      size_t o = (size_t)r * 256 + m;
      float ii = sigf(acc[i][0][r2] + b0);
      float ff = sigf(acc[i][1][r2] + b1);
      float gg = tanh_a(acc[i][2][r2] + b2);
      float oo = sigf(acc[i][3][r2] + b3);
      float c2 = ff * pc[i][r2] + ii * gg;
      HT[o] = f2bf(oo * tanh_a(c2));
      FHR[o] = acc[i][4][r2];
    }
}

// ---------------------------------------------------------------------------
// GEMM3 + node-gate epilogue. A = [HT | xbf-slice] (crows x 768 bf16),
// B = WEX2t (gates i,u,o,f). FHL/FHR + children cbuf prefetched under the
// last MFMA body (T14). lvl>0: write cbuf + parent Ain. lvl==0: d_out fp32.
__global__ __launch_bounds__(256, 2) void k_gemm3(
    const unsigned short* __restrict__ HT, const unsigned short* __restrict__ xnode,
    const unsigned short* __restrict__ Bt,
    const float* __restrict__ FHL, const float* __restrict__ FHR,
    float* __restrict__ cbuf, unsigned short* __restrict__ Ain,
    const float* __restrict__ rel, float* __restrict__ out,
    const float* __restrict__ bix, const float* __restrict__ bih,
    const float* __restrict__ bux, const float* __restrict__ buh,
    const float* __restrict__ box, const float* __restrict__ boh,
    const float* __restrict__ bfx, const float* __restrict__ bfh,
    int base, int v0, int n, int lvl) {
  __shared__ alignas(16) unsigned short As[2][128 * 64];
  __shared__ alignas(16) unsigned short Bs[2][128 * 64];
  int bx, by; swz_blk(bx, by);
  const int t = threadIdx.x;
  const int wave = t >> 6, lane = t & 63;
  const int wm = (wave & 1) * 64, wc = wave >> 1;
  const int m16 = lane & 15, q = lane >> 4;
  const int l8 = lane >> 3, l7 = lane & 7;
  const int gsw = ((l7 ^ l8) * 8);
  const int rowBase = by * 128;
  const unsigned short* Brow = Bt + (size_t)bx * 128 * 768;
  f32x4 acc[4][4] = {};
  const int m = (bx * 2 + wc) * 16 + m16;

  float bi = bix[m] + bih[m];
  float bu = bux[m] + buh[m];
  float bo = box[m] + boh[m];
  float bf = bfx[m] + bfh[m];

  float pfl[4][4], pfr[4][4], pc0[4][4], pc1v[4][4];

  auto stageA = [&](unsigned short* dst, int kb) {
    if (kb < 256) {
      const unsigned short* Arow = HT + (size_t)rowBase * 256;
#pragma unroll
      for (int c = 0; c < 4; ++c) {
        int row8 = wave * 32 + c * 8;
        load16_lds(Arow + (size_t)(row8 + l8) * 256 + kb + gsw, &dst[row8 * 64]);
      }
    } else {
      const unsigned short* Arow = xnode + (size_t)rowBase * 512;
      int k0 = kb - 256;
#pragma unroll
      for (int c = 0; c < 4; ++c) {
        int row8 = wave * 32 + c * 8;
        load16_lds(Arow + (size_t)(row8 + l8) * 512 + k0 + gsw, &dst[row8 * 64]);
      }
    }
  };

  stageA(As[0], 0);
  STAGE(Bs[0], Brow, 768, 128, 0)
#pragma unroll
  for (int ti = 0; ti < 12; ++ti) {
    if (ti < 11) {
      stageA(As[(ti + 1) & 1], (ti + 1) * 64);
      STAGE(Bs[(ti + 1) & 1], Brow, 768, 128, (ti + 1) * 64)
      STEP_SYNC(8)
      if (ti == 10) {
        // Epilogue prefetch: 64 scalar loads (FHL/FHR/cbuf children).
#pragma unroll
        for (int i = 0; i < 4; ++i)
#pragma unroll
          for (int r2 = 0; r2 < 4; ++r2) {
            int r = rowBase + wm + i * 16 + q * 4 + r2;
            int b = r & 127;
            int node = base + v0 + (r >> 7);
            size_t o = (size_t)r * 256 + m;
            size_t co = ((size_t)(2 * node + 1) * 128 + b) * 256 + m;
            pfl[i][r2] = FHL[o];
            pfr[i][r2] = FHR[o];
            pc0[i][r2] = cbuf[co];
            pc1v[i][r2] = cbuf[co + 32768];
          }
      }
    } else {
      STEP_SYNC(63)   // drain the stage loads; epilogue prefetch in flight
    }
    MFMA_BODY(As[ti & 1], Bs[ti & 1], 4, 64)
    __builtin_amdgcn_s_barrier();
  }

#pragma unroll
  for (int i = 0; i < 4; ++i)
#pragma unroll
    for (int r2 = 0; r2 < 4; ++r2) {
      int r = rowBase + wm + i * 16 + q * 4 + r2;
      int vloc = r >> 7, b = r & 127;
      int vg = v0 + vloc;
      int node = base + vg;
      float pf = acc[i][3][r2] + bf;
      float f0 = sigf(pf + pfl[i][r2]);
      float f1 = sigf(pf + pfr[i][r2]);
      float ii = sigf(acc[i][0][r2] + bi);
      float uu = tanh_a(acc[i][1][r2] + bu);
      float oo = sigf(acc[i][2][r2] + bo);
      float cc = ii * uu + f0 * pc0[i][r2] + f1 * pc1v[i][r2];
      float hh = oo * tanh_a(cc);
      if (lvl == 0) {
        out[b * 256 + m] = hh;
      } else {
        cbuf[((size_t)node * 128 + b) * 256 + m] = cc;
        int rowA = (vg & 1) * (n >> 1) * 128 + (vg >> 1) * 128 + b;
        Ain[(size_t)rowA * 320 + m] = f2bf(hh);
        if (m < 64)
          Ain[(size_t)rowA * 320 + 256 + m] = f2bf(rel[((size_t)b * NNODE + node) * 64 + m]);
      }
    }
}

// ---------------------------------------------------------------------------
// Leaf GEMM + epilogue. A = xbf leaf slice (32768 x 512 bf16), B = WL2t
// (gates i,u,o). c = i*u; writes cbuf + level-7 Ain.
__global__ __launch_bounds__(256, 2) void k_leaf(
    const unsigned short* __restrict__ xleaf, const unsigned short* __restrict__ Bt,
    float* __restrict__ cbuf, unsigned short* __restrict__ Ain,
    const float* __restrict__ rel,
    const float* __restrict__ bix, const float* __restrict__ bih,
    const float* __restrict__ bux, const float* __restrict__ buh,
    const float* __restrict__ box, const float* __restrict__ boh) {
  __shared__ alignas(16) unsigned short As[2][128 * 64];
  __shared__ alignas(16) unsigned short Bs[2][96 * 64];
  int bx, by; swz_blk(bx, by);
  const int t = threadIdx.x;
  const int wave = t >> 6, lane = t & 63;
  const int wm = (wave & 1) * 64, wc = wave >> 1;
  const int m16 = lane & 15, q = lane >> 4;
  const int l8 = lane >> 3, l7 = lane & 7;
  const int gsw = ((l7 ^ l8) * 8);
  const int rowBase = by * 128;
  const unsigned short* Arow = xleaf + (size_t)rowBase * 512;
  const unsigned short* Brow = Bt + (size_t)bx * 96 * 512;
  f32x4 acc[4][3] = {};
  const int m = (bx * 2 + wc) * 16 + m16;

  float bi = bix[m] + bih[m];
  float bu = bux[m] + buh[m];
  float bo = box[m] + boh[m];

  STAGE(As[0], Arow, 512, 128, 0)
#pragma unroll
  for (int c = 0; c < 3; ++c) {
    int row8 = wave * 24 + c * 8;
    load16_lds(Brow + (size_t)(row8 + l8) * 512 + 0 + gsw, &Bs[0][row8 * 64]);
  }
#pragma unroll
  for (int ti = 0; ti < 8; ++ti) {
    if (ti < 7) {
      int kn = (ti + 1) * 64;
      STAGE(As[(ti + 1) & 1], Arow, 512, 128, kn)
#pragma unroll
      for (int c = 0; c < 3; ++c) {
        int row8 = wave * 24 + c * 8;
        load16_lds(Brow + (size_t)(row8 + l8) * 512 + kn + gsw, &Bs[(ti + 1) & 1][row8 * 64]);
      }
      STEP_SYNC(7)
    } else {
      STEP_SYNC(0)
    }
    MFMA_BODY(As[ti & 1], Bs[ti & 1], 3, 48)
    __builtin_amdgcn_s_barrier();
  }

#pragma unroll
  for (int i = 0; i < 4; ++i)
#pragma unroll
    for (int r2 = 0; r2 < 4; ++r2) {
      int r = rowBase + wm + i * 16 + q * 4 + r2;
      int vg = r >> 7, b = r & 127;
      int node = 255 + vg;
      float ii = sigf(acc[i][0][r2] + bi);
      float uu = tanh_a(acc[i][1][r2] + bu);
      float oo = sigf(acc[i][2][r2] + bo);
      float cc = ii * uu;
      float hh = oo * tanh_a(cc);
      cbuf[((size_t)node * 128 + b) * 256 + m] = cc;
      int rowA = (vg & 1) * 16384 + (vg >> 1) * 128 + b;
      Ain[(size_t)rowA * 320 + m] = f2bf(hh);
      if (m < 64)
        Ain[(size_t)rowA * 320 + 256 + m] = f2bf(rel[((size_t)b * NNODE + node) * 64 + m]);
    }
}

// ---------------------------------------------------------------------------
extern "C" void kernel_launch(void* const* d_in, const int* in_sizes, int n_in,
                              void* d_out, int out_size, void* d_ws, size_t ws_size,
                              hipStream_t stream) {
  const float* wte = (const float*)d_in[0];
  const float* rel = (const float*)d_in[1];
  const float* Wix = (const float*)d_in[3];
  const float* bix = (const float*)d_in[4];
  const float* Wfx = (const float*)d_in[5];
  const float* bfx = (const float*)d_in[6];
  const float* Wux = (const float*)d_in[7];
  const float* bux = (const float*)d_in[8];
  const float* Wox = (const float*)d_in[9];
  const float* box = (const float*)d_in[10];
  const float* Wih = (const float*)d_in[11];
  const float* bih = (const float*)d_in[12];
  const float* Wfh = (const float*)d_in[13];
  const float* bfh = (const float*)d_in[14];
  const float* Wuh = (const float*)d_in[15];
  const float* buh = (const float*)d_in[16];
  const float* Woh = (const float*)d_in[17];
  const float* boh = (const float*)d_in[18];
  const float* Wsi = (const float*)d_in[19];
  const float* Wsh = (const float*)d_in[20];
  const float* bsi = (const float*)d_in[21];
  const float* bsh = (const float*)d_in[22];
  float* out = (float*)d_out;
  (void)in_sizes; (void)n_in; (void)out_size;

  int INT_MAXN;
  if (ws_size >= (size_t)310 * 1024 * 1024)      INT_MAXN = 128;
  else if (ws_size >= (size_t)200 * 1024 * 1024) INT_MAXN = 32;
  else                                           INT_MAXN = 8;
  const int crowsMax = INT_MAXN * 128;

  char* ws = (char*)d_ws;
  size_t off = 0;
  auto alloc = [&](size_t bytes) {
    size_t o = off; off += (bytes + 255) & ~(size_t)255; return o;
  };
  unsigned short* xbf  = (unsigned short*)(ws + alloc((size_t)NNODE * 128 * 512 * 2));
  float*          cbuf = (float*)         (ws + alloc((size_t)NNODE * 128 * 256 * 4));
  unsigned short* Ain  = (unsigned short*)(ws + alloc((size_t)32768 * 320 * 2));
  unsigned short* WL2t = (unsigned short*)(ws + alloc((size_t)768 * 512 * 2));
  unsigned short* WA2t = (unsigned short*)(ws + alloc((size_t)1280 * 320 * 2));
  unsigned short* WG2t = (unsigned short*)(ws + alloc((size_t)1280 * 576 * 2));
  unsigned short* WEX2t= (unsigned short*)(ws + alloc((size_t)1024 * 768 * 2));
  unsigned short* h1   = (unsigned short*)(ws + alloc((size_t)crowsMax * 256 * 2));
  float*          c1   = (float*)         (ws + alloc((size_t)crowsMax * 256 * 4));
  float*          FHL  = (float*)         (ws + alloc((size_t)crowsMax * 256 * 4));
  float*          FHR  = (float*)         (ws + alloc((size_t)crowsMax * 256 * 4));
  unsigned short* HT   = (unsigned short*)(ws + alloc((size_t)crowsMax * 256 * 2));

  k_prep_x<<<32704, 256, 0, stream>>>(wte, xbf);
  k_prep_w<<<9088, 256, 0, stream>>>(Wix, Wux, Wox, Wfx, Wih, Wuh, Woh, Wfh,
                                     Wsi, Wsh, WL2t, WA2t, WG2t, WEX2t);

  // Leaves: one fused GEMM over xbf rows [255*128, 511*128).
  k_leaf<<<dim3(8, 256), 256, 0, stream>>>(xbf + (size_t)255 * 128 * 512, WL2t,
                                           cbuf, Ain, rel, bix, bih, bux, buh, box, boh);

  // Internal levels 7..0, 3 fused launches per chunk.
  for (int lvl = 7; lvl >= 0; --lvl) {
    int n = 1 << lvl;
    int base = n - 1;
    int cn = (n < INT_MAXN) ? n : INT_MAXN;
    for (int v0 = 0; v0 < n; v0 += cn) {
      const unsigned short* AinL = Ain + (size_t)(v0 * 128) * 320;
      const unsigned short* AinR = Ain + (size_t)((n + v0) * 128) * 320;
      const unsigned short* xnode = xbf + (size_t)(base + v0) * 128 * 512;
      k_gemm1<<<dim3(8, cn), 256, 0, stream>>>(AinL, WA2t, h1, c1, FHL, bsi, bsh);
      k_gemm2<<<dim3(8, cn), 256, 0, stream>>>(h1, AinR, WG2t, c1, HT, FHR, bsi, bsh);
      k_gemm3<<<dim3(8, cn), 256, 0, stream>>>(HT, xnode, WEX2t, FHL, FHR, cbuf, Ain,
                                               rel, out, bix, bih, bux, buh, box, boh,
                                               bfx, bfh, base, v0, n, lvl);
    }
  }
}